// Round 1
// baseline (714.067 us; speedup 1.0000x reference)
//
#include <hip/hip_runtime.h>
#include <cstdint>

#define EPSF 1e-5f

__device__ __forceinline__ float sigmoidf_(float x){ return 1.f/(1.f+__expf(-x)); }
__device__ __forceinline__ float siluf_(float x){ return x*sigmoidf_(x); }
__device__ __forceinline__ float softplusf_(float x){ return fmaxf(x,0.f) + log1pf(__expf(-fabsf(x))); }
__device__ __forceinline__ int mapdir_(int dir, int l){
  int lt = (dir & 2) ? (1023 - l) : l;
  return (dir & 1) ? (((lt & 31) << 5) | (lt >> 5)) : lt;
}

// ---------------- wavelet decompose: x[:,0:192] (B,192,64,64) -> xll pos-major (B*1024,192),
// ---------------- xhigh pos-major (B*1024,576) with hc = 3*c + (f-1)
__global__ __launch_bounds__(256) void wav_dec(const float* __restrict__ x,
                                               float* __restrict__ xll, float* __restrict__ xhigh){
  int b = blockIdx.x >> 5, i = blockIdx.x & 31;
  __shared__ float r0[64*65];
  __shared__ float r1[64*65];
  int tid = threadIdx.x;
  for (int c0 = 0; c0 < 192; c0 += 64){
    if (c0) __syncthreads();
    for (int t = tid; t < 1024; t += 256){
      int cc = t >> 4, col4 = (t & 15)*4;
      const float* p0 = &x[(((size_t)b*320 + c0+cc)*64 + 2*i)*64 + col4];
      const float* p1 = &x[(((size_t)b*320 + c0+cc)*64 + 2*i+1)*64 + col4];
      float4 a = *(const float4*)p0;
      float4 bb = *(const float4*)p1;
      r0[cc*65+col4+0]=a.x; r0[cc*65+col4+1]=a.y; r0[cc*65+col4+2]=a.z; r0[cc*65+col4+3]=a.w;
      r1[cc*65+col4+0]=bb.x; r1[cc*65+col4+1]=bb.y; r1[cc*65+col4+2]=bb.z; r1[cc*65+col4+3]=bb.w;
    }
    __syncthreads();
    for (int t = tid; t < 2048; t += 256){
      int cl = t & 63, j = t >> 6;
      float a  = r0[cl*65 + 2*j], bv = r0[cl*65 + 2*j + 1];
      float cv = r1[cl*65 + 2*j], dv = r1[cl*65 + 2*j + 1];
      float f0 = 0.5f*(a+bv+cv+dv);
      float f1 = 0.5f*(a+bv-cv-dv);
      float f2 = 0.5f*(a-bv+cv-dv);
      float f3 = 0.5f*(a-bv-cv+dv);
      int l = i*32 + j; int c = c0 + cl;
      xll[((size_t)b*1024 + l)*192 + c] = f0;
      float* hp = &xhigh[((size_t)b*1024 + l)*576 + 3*c];
      hp[0]=f1; hp[1]=f2; hp[2]=f3;
    }
  }
}

// ---------------- LN over 192 channels per position
__global__ __launch_bounds__(64) void ln192(const float* __restrict__ xll,
                                            const float* __restrict__ g, const float* __restrict__ bt,
                                            float* __restrict__ xln){
  int p = blockIdx.x; int lane = threadIdx.x;
  const float* row = xll + (size_t)p*192;
  float v0 = row[lane], v1 = row[lane+64], v2 = row[lane+128];
  float s = v0+v1+v2, s2 = v0*v0+v1*v1+v2*v2;
  #pragma unroll
  for (int off=32; off; off>>=1){ s += __shfl_xor(s, off, 64); s2 += __shfl_xor(s2, off, 64); }
  float mean = s*(1.f/192.f);
  float var = s2*(1.f/192.f) - mean*mean;
  float rstd = rsqrtf(var + EPSF);
  float* o = xln + (size_t)p*192;
  o[lane]     = (v0-mean)*rstd*g[lane]     + bt[lane];
  o[lane+64]  = (v1-mean)*rstd*g[lane+64]  + bt[lane+64];
  o[lane+128] = (v2-mean)*rstd*g[lane+128] + bt[lane+128];
}

// ---------------- generic tiled GEMM: C[M,N] = A[M,K] * W[N,K]^T
// MODE 0: plain, C pos-major. MODE 2: A scaled by gate[b(m)][k], epilogue BN -> pos-major.
// MODE 3: A = [A1 pos-major (k<192) | x channel-major (k>=192)], epilogue BN + residual,
//         writes channel-major d_out.
template<int MODE>
__global__ __launch_bounds__(256) void gemm_main(
    const float* __restrict__ A, const float* __restrict__ W, float* __restrict__ C,
    int M, int N, int K, int lda,
    const float* __restrict__ gate, const float* __restrict__ bn, const float* __restrict__ xres)
{
  __shared__ float As[32][128];
  __shared__ float Ws[32][64];
  int tid = threadIdx.x;
  int tx = tid & 15, ty = tid >> 4;
  int m0 = blockIdx.x * 128, n0 = blockIdx.y * 64;
  float acc[8][4];
  #pragma unroll
  for (int i=0;i<8;i++)
    #pragma unroll
    for (int j=0;j<4;j++) acc[i][j]=0.f;

  for (int k0 = 0; k0 < K; k0 += 32) {
    if (MODE==3 && k0 >= 192) {
      #pragma unroll
      for (int s=0;s<16;s++){
        int idx = tid + 256*s;
        int m = idx & 127, kk = idx >> 7;
        int gm = m0 + m;
        int b = gm >> 12, hw = gm & 4095;
        As[kk][m] = xres[((size_t)(b*320 + k0 + kk))*4096 + hw];
      }
    } else {
      #pragma unroll
      for (int r=0;r<4;r++){
        int fid = tid + 256*r;
        int m = fid >> 3, k4 = (fid & 7)*4;
        float4 v = *(const float4*)&A[(size_t)(m0+m)*lda + k0 + k4];
        if (MODE==2){
          int b = (m0+m) >> 10;
          v.x *= gate[b*576 + k0+k4+0];
          v.y *= gate[b*576 + k0+k4+1];
          v.z *= gate[b*576 + k0+k4+2];
          v.w *= gate[b*576 + k0+k4+3];
        }
        As[k4+0][m]=v.x; As[k4+1][m]=v.y; As[k4+2][m]=v.z; As[k4+3][m]=v.w;
      }
    }
    #pragma unroll
    for (int r=0;r<2;r++){
      int fid = tid + 256*r;
      int n = fid >> 3, k4 = (fid & 7)*4;
      float4 v = *(const float4*)&W[(size_t)(n0+n)*K + k0 + k4];
      Ws[k4+0][n]=v.x; Ws[k4+1][n]=v.y; Ws[k4+2][n]=v.z; Ws[k4+3][n]=v.w;
    }
    __syncthreads();
    #pragma unroll
    for (int kk=0;kk<32;kk++){
      float4 a0 = *(float4*)&As[kk][ty*8];
      float4 a1 = *(float4*)&As[kk][ty*8+4];
      float4 bf = *(float4*)&Ws[kk][tx*4];
      float av[8] = {a0.x,a0.y,a0.z,a0.w,a1.x,a1.y,a1.z,a1.w};
      float bv[4] = {bf.x,bf.y,bf.z,bf.w};
      #pragma unroll
      for (int i=0;i<8;i++)
        #pragma unroll
        for (int j=0;j<4;j++)
          acc[i][j] = fmaf(av[i], bv[j], acc[i][j]);
    }
    __syncthreads();
  }
  if (MODE==0){
    #pragma unroll
    for (int i=0;i<8;i++){
      float4 o = make_float4(acc[i][0],acc[i][1],acc[i][2],acc[i][3]);
      *(float4*)&C[(size_t)(m0+ty*8+i)*N + n0 + tx*4] = o;
    }
  } else if (MODE==2){
    float sc[4], sh[4];
    #pragma unroll
    for (int j=0;j<4;j++){
      int o = n0 + tx*4 + j;
      float gg = bn[o], bb = bn[N+o], mu = bn[2*N+o], var = bn[3*N+o];
      sc[j] = gg * rsqrtf(var + EPSF);
      sh[j] = bb - mu*sc[j];
    }
    #pragma unroll
    for (int i=0;i<8;i++){
      float4 o = make_float4(fmaf(acc[i][0],sc[0],sh[0]), fmaf(acc[i][1],sc[1],sh[1]),
                             fmaf(acc[i][2],sc[2],sh[2]), fmaf(acc[i][3],sc[3],sh[3]));
      *(float4*)&C[(size_t)(m0+ty*8+i)*N + n0 + tx*4] = o;
    }
  } else if (MODE==3){
    int gm0 = m0 + ty*8;
    int b = gm0 >> 12, hw0 = gm0 & 4095;
    #pragma unroll
    for (int j=0;j<4;j++){
      int o = n0 + tx*4 + j;
      float gg = bn[o], bb = bn[N+o], mu = bn[2*N+o], var = bn[3*N+o];
      float sc = gg * rsqrtf(var + EPSF);
      float sh = bb - mu*sc;
      size_t base = ((size_t)(b*320 + o))*4096 + hw0;
      #pragma unroll
      for (int h=0;h<2;h++){
        float4 xr = *(const float4*)&xres[base + h*4];
        float4 ov;
        ov.x = xr.x + fmaf(acc[h*4+0][j], sc, sh);
        ov.y = xr.y + fmaf(acc[h*4+1][j], sc, sh);
        ov.z = xr.z + fmaf(acc[h*4+2][j], sc, sh);
        ov.w = xr.w + fmaf(acc[h*4+3][j], sc, sh);
        *(float4*)&C[base + h*4] = ov;
      }
    }
  }
}

// ---------------- depthwise 3x3 + bias + SiLU on xm (first 384 cols of xz rows)
__global__ __launch_bounds__(384) void dwconv_silu(const float* __restrict__ xz,
                                                   const float* __restrict__ cw, const float* __restrict__ cb,
                                                   float* __restrict__ xconv){
  int bl = blockIdx.x; int b = bl >> 10, l = bl & 1023;
  int i = l >> 5, j = l & 31;
  int d = threadIdx.x;
  float w[9];
  #pragma unroll
  for (int t=0;t<9;t++) w[t] = cw[d*9+t];
  float acc = cb[d];
  #pragma unroll
  for (int di=-1;di<=1;di++){
    int ii = i+di; if (ii < 0 || ii > 31) continue;
    #pragma unroll
    for (int dj=-1;dj<=1;dj++){
      int jj = j+dj; if (jj < 0 || jj > 31) continue;
      acc += w[(di+1)*3 + (dj+1)] * xz[((size_t)(b*1024 + ii*32 + jj))*768 + d];
    }
  }
  xconv[(size_t)bl*384 + d] = siluf_(acc);
}

// ---------------- x_proj: per (b,dir) GEMM: xdbl[bk][c<44][l] = sum_d xconv[b, map(l), d] * xpw[dir][c][d]
__global__ __launch_bounds__(256) void gemm_xproj(const float* __restrict__ xconv,
                                                  const float* __restrict__ xpw, float* __restrict__ xdbl){
  __shared__ float As[32][128];
  __shared__ float Ws[32][64];
  int tid = threadIdx.x;
  int tx = tid & 15, ty = tid >> 4;
  int m0 = blockIdx.x * 128;
  int bk = blockIdx.z; int b = bk >> 2, dir = bk & 3;
  const float* Wk = xpw + (size_t)dir*44*384;
  float acc[8][4];
  #pragma unroll
  for (int i=0;i<8;i++)
    #pragma unroll
    for (int j=0;j<4;j++) acc[i][j]=0.f;
  for (int k0=0;k0<384;k0+=32){
    #pragma unroll
    for (int r=0;r<4;r++){
      int fid = tid + 256*r;
      int m = fid >> 3, k4 = (fid & 7)*4;
      int l = m0 + m;
      int row = b*1024 + mapdir_(dir, l);
      float4 v = *(const float4*)&xconv[(size_t)row*384 + k0 + k4];
      As[k4+0][m]=v.x; As[k4+1][m]=v.y; As[k4+2][m]=v.z; As[k4+3][m]=v.w;
    }
    #pragma unroll
    for (int r=0;r<2;r++){
      int fid = tid + 256*r;
      int n = fid >> 3, k4 = (fid & 7)*4;
      float4 v = (n < 44) ? *(const float4*)&Wk[(size_t)n*384 + k0 + k4] : make_float4(0.f,0.f,0.f,0.f);
      Ws[k4+0][n]=v.x; Ws[k4+1][n]=v.y; Ws[k4+2][n]=v.z; Ws[k4+3][n]=v.w;
    }
    __syncthreads();
    #pragma unroll
    for (int kk=0;kk<32;kk++){
      float4 a0 = *(float4*)&As[kk][ty*8];
      float4 a1 = *(float4*)&As[kk][ty*8+4];
      float4 bf = *(float4*)&Ws[kk][tx*4];
      float av[8] = {a0.x,a0.y,a0.z,a0.w,a1.x,a1.y,a1.z,a1.w};
      float bv[4] = {bf.x,bf.y,bf.z,bf.w};
      #pragma unroll
      for (int i=0;i<8;i++)
        #pragma unroll
        for (int j=0;j<4;j++)
          acc[i][j] = fmaf(av[i], bv[j], acc[i][j]);
    }
    __syncthreads();
  }
  float* Cb = xdbl + (size_t)bk*44*1024;
  #pragma unroll
  for (int j=0;j<4;j++){
    int c = tx*4 + j;
    if (c < 44){
      float4 o0 = make_float4(acc[0][j],acc[1][j],acc[2][j],acc[3][j]);
      float4 o1 = make_float4(acc[4][j],acc[5][j],acc[6][j],acc[7][j]);
      *(float4*)&Cb[(size_t)c*1024 + m0 + ty*8]     = o0;
      *(float4*)&Cb[(size_t)c*1024 + m0 + ty*8 + 4] = o1;
    }
  }
}

// ---------------- selective scan: pass A (chunk summaries)
__global__ __launch_bounds__(256) void scan_chunks(const float* __restrict__ xconv, const float* __restrict__ xdbl,
    const float* __restrict__ dtw_all, const float* __restrict__ dtb_all, const float* __restrict__ alog_all,
    float* __restrict__ Pa, float* __restrict__ Sa){
  int dl = threadIdx.x & 63, cs = threadIdx.x >> 6;
  int d = blockIdx.x*64 + dl;
  int chunk = blockIdx.y*4 + cs;
  int bk = blockIdx.z; int b = bk >> 2, k = bk & 3;
  float dtw[12];
  #pragma unroll
  for (int r=0;r<12;r++) dtw[r] = dtw_all[(size_t)(k*384 + d)*12 + r];
  float dtb = dtb_all[k*384 + d];
  float Ar[16];
  #pragma unroll
  for (int n=0;n<16;n++) Ar[n] = -__expf(alog_all[(size_t)(k*384 + d)*16 + n]);
  float h[16], P[16];
  #pragma unroll
  for (int n=0;n<16;n++){ h[n]=0.f; P[n]=1.f; }
  const float* xd = xdbl + (size_t)bk*44*1024;
  int l0 = chunk*32;
  for (int li=0; li<32; li++){
    int l = l0 + li;
    float u = xconv[((size_t)(b*1024 + mapdir_(k, l)))*384 + d];
    float dr = dtb;
    #pragma unroll
    for (int r=0;r<12;r++) dr = fmaf(dtw[r], xd[r*1024 + l], dr);
    float delta = softplusf_(dr);
    float du = delta * u;
    #pragma unroll
    for (int n=0;n<16;n++){
      float e = __expf(delta * Ar[n]);
      h[n] = fmaf(e, h[n], du * xd[(12+n)*1024 + l]);
      P[n] *= e;
    }
  }
  size_t base = (((size_t)bk*32 + chunk)*16)*384 + d;
  #pragma unroll
  for (int n=0;n<16;n++){ Pa[base + (size_t)n*384] = P[n]; Sa[base + (size_t)n*384] = h[n]; }
}

// ---------------- selective scan: pass B (chain chunk states)
__global__ __launch_bounds__(256) void scan_chain(const float* __restrict__ Pa, const float* __restrict__ Sa,
                                                  float* __restrict__ Hinit){
  int dl = threadIdx.x & 63, nl = threadIdx.x >> 6;
  int d = blockIdx.x*64 + dl;
  int n = blockIdx.y*4 + nl;
  int bk = blockIdx.z;
  float h = 0.f;
  for (int c=0;c<32;c++){
    size_t idx = (((size_t)bk*32 + c)*16 + n)*384 + d;
    Hinit[idx] = h;
    h = fmaf(Pa[idx], h, Sa[idx]);
  }
}

// ---------------- selective scan: pass C (emit y)
__global__ __launch_bounds__(256) void scan_emit(const float* __restrict__ xconv, const float* __restrict__ xdbl,
    const float* __restrict__ dtw_all, const float* __restrict__ dtb_all, const float* __restrict__ alog_all,
    const float* __restrict__ Ds, const float* __restrict__ Hinit, float* __restrict__ yout){
  int dl = threadIdx.x & 63, cs = threadIdx.x >> 6;
  int d = blockIdx.x*64 + dl;
  int chunk = blockIdx.y*4 + cs;
  int bk = blockIdx.z; int b = bk >> 2, k = bk & 3;
  float dtw[12];
  #pragma unroll
  for (int r=0;r<12;r++) dtw[r] = dtw_all[(size_t)(k*384 + d)*12 + r];
  float dtb = dtb_all[k*384 + d];
  float Dv = Ds[k*384 + d];
  float Ar[16];
  #pragma unroll
  for (int n=0;n<16;n++) Ar[n] = -__expf(alog_all[(size_t)(k*384 + d)*16 + n]);
  float h[16];
  size_t hbase = (((size_t)bk*32 + chunk)*16)*384 + d;
  #pragma unroll
  for (int n=0;n<16;n++) h[n] = Hinit[hbase + (size_t)n*384];
  const float* xd = xdbl + (size_t)bk*44*1024;
  int l0 = chunk*32;
  for (int li=0; li<32; li++){
    int l = l0 + li;
    float u = xconv[((size_t)(b*1024 + mapdir_(k, l)))*384 + d];
    float dr = dtb;
    #pragma unroll
    for (int r=0;r<12;r++) dr = fmaf(dtw[r], xd[r*1024 + l], dr);
    float delta = softplusf_(dr);
    float du = delta * u;
    float y = Dv * u;
    #pragma unroll
    for (int n=0;n<16;n++){
      float e = __expf(delta * Ar[n]);
      h[n] = fmaf(e, h[n], du * xd[(12+n)*1024 + l]);
      y = fmaf(h[n], xd[(28+n)*1024 + l], y);
    }
    yout[((size_t)bk*1024 + l)*384 + d] = y;
  }
}

// ---------------- merge 4 directions + LN(384) + *silu(z) -> gated pos-major
__global__ __launch_bounds__(64) void merge_ln(const float* __restrict__ ysc, const float* __restrict__ xz,
    const float* __restrict__ ong, const float* __restrict__ onb, float* __restrict__ gated){
  int bl = blockIdx.x; int b = bl >> 10, l = bl & 1023;
  int lane = threadIdx.x;
  int p1 = ((l & 31) << 5) | (l >> 5);
  const float* y0 = ysc + ((size_t)(b*4+0)*1024 + l)*384;
  const float* y1 = ysc + ((size_t)(b*4+1)*1024 + p1)*384;
  const float* y2 = ysc + ((size_t)(b*4+2)*1024 + (1023-l))*384;
  const float* y3 = ysc + ((size_t)(b*4+3)*1024 + (1023-p1))*384;
  float v[6]; float s = 0.f, s2 = 0.f;
  #pragma unroll
  for (int r=0;r<6;r++){
    int d = lane + 64*r;
    float t = y0[d] + y1[d] + y2[d] + y3[d];
    v[r] = t; s += t; s2 += t*t;
  }
  #pragma unroll
  for (int off=32; off; off>>=1){ s += __shfl_xor(s, off, 64); s2 += __shfl_xor(s2, off, 64); }
  float mean = s*(1.f/384.f);
  float var = s2*(1.f/384.f) - mean*mean;
  float rstd = rsqrtf(var + EPSF);
  const float* zrow = xz + (size_t)bl*768 + 384;
  float* grow = gated + (size_t)bl*384;
  #pragma unroll
  for (int r=0;r<6;r++){
    int d = lane + 64*r;
    float z = zrow[d];
    grow[d] = ((v[r]-mean)*rstd*ong[d] + onb[d]) * siluf_(z);
  }
}

// ---------------- high path depthwise 3x3 + BN (+ReLU)
template<int RELU>
__global__ __launch_bounds__(576) void dwconv_bn(const float* __restrict__ hin,
    const float* __restrict__ dw, const float* __restrict__ bn, float* __restrict__ hout){
  int bl = blockIdx.x; int b = bl >> 10, l = bl & 1023;
  int i = l >> 5, j = l & 31;
  int d = threadIdx.x;
  float w[9];
  #pragma unroll
  for (int t=0;t<9;t++) w[t] = dw[d*9+t];
  float acc = 0.f;
  #pragma unroll
  for (int di=-1;di<=1;di++){
    int ii = i+di; if (ii < 0 || ii > 31) continue;
    #pragma unroll
    for (int dj=-1;dj<=1;dj++){
      int jj = j+dj; if (jj < 0 || jj > 31) continue;
      acc += w[(di+1)*3 + (dj+1)] * hin[((size_t)(b*1024 + ii*32 + jj))*576 + d];
    }
  }
  float sc = bn[d] * rsqrtf(bn[3*576+d] + EPSF);
  float vv = (acc - bn[2*576+d])*sc + bn[576+d];
  if (RELU) vv = fmaxf(vv, 0.f);
  hout[(size_t)bl*576 + d] = vv;
}

// ---------------- spatial mean of h2 per (b, d)
__global__ __launch_bounds__(256) void mean576(const float* __restrict__ h2, float* __restrict__ smean){
  __shared__ float red[256];
  int dg = blockIdx.x, b = blockIdx.y;
  int dl = threadIdx.x & 63, lq = threadIdx.x >> 6;
  int d = dg*64 + dl;
  float ps = 0.f;
  for (int l = lq; l < 1024; l += 4)
    ps += h2[((size_t)(b*1024 + l))*576 + d];
  red[threadIdx.x] = ps;
  __syncthreads();
  if (threadIdx.x < 64){
    float ssum = red[threadIdx.x] + red[threadIdx.x+64] + red[threadIdx.x+128] + red[threadIdx.x+192];
    smean[b*576 + dg*64 + threadIdx.x] = ssum * (1.f/1024.f);
  }
}

// ---------------- SE gate
__global__ __launch_bounds__(256) void se_gate(const float* __restrict__ smean,
    const float* __restrict__ rw, const float* __restrict__ rb,
    const float* __restrict__ ew, const float* __restrict__ eb, float* __restrict__ gate4){
  __shared__ float s_ld[576];
  __shared__ float r_ld[144];
  int b = blockIdx.x, t = threadIdx.x;
  for (int c=t; c<576; c+=256) s_ld[c] = smean[b*576+c];
  __syncthreads();
  if (t < 144){
    float a = rb[t];
    for (int c=0;c<576;c++) a = fmaf(rw[(size_t)t*576+c], s_ld[c], a);
    r_ld[t] = fmaxf(a, 0.f);
  }
  __syncthreads();
  for (int d=t; d<576; d+=256){
    float a = eb[d];
    for (int j=0;j<144;j++) a = fmaf(ew[(size_t)d*144+j], r_ld[j], a);
    gate4[b*576+d] = sigmoidf_(a);
  }
}

// ---------------- wavelet reconstruct into A1 pos-major (B*4096, 192)
__global__ __launch_bounds__(192) void recon(const float* __restrict__ xllout, const float* __restrict__ h2o,
                                             float* __restrict__ A1){
  int bl = blockIdx.x; int b = bl >> 10, lr = bl & 1023;
  int c = threadIdx.x;
  int i = lr >> 5, j = lr & 31;
  float f0 = xllout[(size_t)bl*192 + c];
  const float* hp = &h2o[(size_t)bl*576 + 3*c];
  float f1 = hp[0], f2 = hp[1], f3 = hp[2];
  float v00 = 0.5f*(f0 - f1 - f2 + f3);
  float v01 = 0.5f*(f0 - f1 + f2 - f3);
  float v10 = 0.5f*(f0 + f1 - f2 - f3);
  float v11 = 0.5f*(f0 + f1 + f2 + f3);
  size_t base = ((size_t)b*4096 + (size_t)(2*i)*64 + 2*j)*192 + c;
  A1[base]            = v00;
  A1[base + 192]      = v01;
  A1[base + 64*192]   = v10;
  A1[base + 65*192]   = v11;
}

extern "C" void kernel_launch(void* const* d_in, const int* in_sizes, int n_in,
                              void* d_out, int out_size, void* d_ws, size_t ws_size,
                              hipStream_t stream) {
  const float* x         = (const float*)d_in[0];
  const float* in_proj_w = (const float*)d_in[1];
  const float* conv_w    = (const float*)d_in[2];
  const float* conv_b    = (const float*)d_in[3];
  const float* x_proj_w  = (const float*)d_in[4];
  const float* dt_proj_w = (const float*)d_in[5];
  const float* dt_proj_b = (const float*)d_in[6];
  const float* A_logs    = (const float*)d_in[7];
  const float* Dsp       = (const float*)d_in[8];
  const float* out_norm_g= (const float*)d_in[9];
  const float* out_norm_b= (const float*)d_in[10];
  const float* out_proj_w= (const float*)d_in[11];
  const float* norm_g    = (const float*)d_in[12];
  const float* norm_b    = (const float*)d_in[13];
  const float* lp_dw1_w  = (const float*)d_in[14];
  const float* lp_bn1    = (const float*)d_in[15];
  const float* lp_dw2_w  = (const float*)d_in[16];
  const float* lp_bn2    = (const float*)d_in[17];
  const float* se_rw     = (const float*)d_in[18];
  const float* se_rb     = (const float*)d_in[19];
  const float* se_ew     = (const float*)d_in[20];
  const float* se_eb     = (const float*)d_in[21];
  const float* lp_pw_w   = (const float*)d_in[22];
  const float* lp_bn3    = (const float*)d_in[23];
  const float* proj_w    = (const float*)d_in[24];
  const float* proj_bn   = (const float*)d_in[25];
  float* out = (float*)d_out;
  float* ws = (float*)d_ws;

  float* xll    = ws;                  // 786432
  float* xhigh  = xll + 786432;        // 2359296   (reused as h2)
  float* xln    = xhigh + 2359296;     // 786432
  float* xz     = xln + 786432;        // 3145728   (reused as A1)
  float* xconv  = xz + 3145728;        // 1572864
  float* xdbl   = xconv + 1572864;     // 720896
  float* Pa     = xdbl + 720896;       // 3145728   (Pa+Sa reused as yscan)
  float* Sa     = Pa + 3145728;        // 3145728
  float* Hinit  = Sa + 3145728;        // 3145728   (reused as gated)
  float* h1     = Hinit + 3145728;     // 2359296   (reused as h2o)
  float* xllout = h1 + 2359296;        // 786432
  float* smean  = xllout + 786432;     // 2304
  float* gate4  = smean + 2304;        // 2304
  float* yscan  = Pa;
  float* gated  = Hinit;
  float* h2     = xhigh;
  float* h2o    = h1;
  float* A1     = xz;

  wav_dec<<<dim3(128), dim3(256), 0, stream>>>(x, xll, xhigh);
  ln192<<<dim3(4096), dim3(64), 0, stream>>>(xll, norm_g, norm_b, xln);
  gemm_main<0><<<dim3(32,12), dim3(256), 0, stream>>>(xln, in_proj_w, xz, 4096, 768, 192, 192,
                                                      nullptr, nullptr, nullptr);
  dwconv_silu<<<dim3(4096), dim3(384), 0, stream>>>(xz, conv_w, conv_b, xconv);
  gemm_xproj<<<dim3(8,1,16), dim3(256), 0, stream>>>(xconv, x_proj_w, xdbl);
  scan_chunks<<<dim3(6,8,16), dim3(256), 0, stream>>>(xconv, xdbl, dt_proj_w, dt_proj_b, A_logs, Pa, Sa);
  scan_chain<<<dim3(6,4,16), dim3(256), 0, stream>>>(Pa, Sa, Hinit);
  scan_emit<<<dim3(6,8,16), dim3(256), 0, stream>>>(xconv, xdbl, dt_proj_w, dt_proj_b, A_logs, Dsp, Hinit, yscan);
  merge_ln<<<dim3(4096), dim3(64), 0, stream>>>(yscan, xz, out_norm_g, out_norm_b, gated);
  gemm_main<0><<<dim3(32,3), dim3(256), 0, stream>>>(gated, out_proj_w, xllout, 4096, 192, 384, 384,
                                                     nullptr, nullptr, nullptr);
  dwconv_bn<1><<<dim3(4096), dim3(576), 0, stream>>>(xhigh, lp_dw1_w, lp_bn1, h1);
  dwconv_bn<0><<<dim3(4096), dim3(576), 0, stream>>>(h1, lp_dw2_w, lp_bn2, h2);
  mean576<<<dim3(9,4), dim3(256), 0, stream>>>(h2, smean);
  se_gate<<<dim3(4), dim3(256), 0, stream>>>(smean, se_rw, se_rb, se_ew, se_eb, gate4);
  gemm_main<2><<<dim3(32,9), dim3(256), 0, stream>>>(h2, lp_pw_w, h2o, 4096, 576, 576, 576,
                                                     gate4, lp_bn3, nullptr);
  recon<<<dim3(4096), dim3(192), 0, stream>>>(xllout, h2o, A1);
  gemm_main<3><<<dim3(128,5), dim3(256), 0, stream>>>(A1, proj_w, out, 16384, 320, 320, 192,
                                                      nullptr, proj_bn, x);
}

// Round 5
// 545.199 us; speedup vs baseline: 1.3097x; 1.3097x over previous
//
#include <hip/hip_runtime.h>
#include <cstdint>

#define EPSF 1e-5f

typedef __attribute__((ext_vector_type(8))) short short8;
typedef __attribute__((ext_vector_type(4))) float f32x4;

__device__ __forceinline__ float sigmoidf_(float x){ return 1.f/(1.f+__expf(-x)); }
__device__ __forceinline__ float siluf_(float x){ return x*sigmoidf_(x); }
__device__ __forceinline__ float softplusf_(float x){ return fmaxf(x,0.f) + log1pf(__expf(-fabsf(x))); }
__device__ __forceinline__ int mapdir_(int dir, int l){
  int lt = (dir & 2) ? (1023 - l) : l;
  return (dir & 1) ? (((lt & 31) << 5) | (lt >> 5)) : lt;
}
__device__ __forceinline__ unsigned short f2bf_(float f){
  unsigned int u = __float_as_uint(f);
  u = (u + 0x7FFFu + ((u >> 16) & 1u)) >> 16;
  return (unsigned short)u;
}

// ---------------- wavelet decompose: x[:,0:192] (B,192,64,64) -> xll pos-major (B*1024,192),
// ---------------- xhigh pos-major (B*1024,576) with hc = 3*c + (f-1)
__global__ __launch_bounds__(256) void wav_dec(const float* __restrict__ x,
                                               float* __restrict__ xll, float* __restrict__ xhigh){
  int b = blockIdx.x >> 5, i = blockIdx.x & 31;
  __shared__ float r0[64*65];
  __shared__ float r1[64*65];
  int tid = threadIdx.x;
  for (int c0 = 0; c0 < 192; c0 += 64){
    if (c0) __syncthreads();
    for (int t = tid; t < 1024; t += 256){
      int cc = t >> 4, col4 = (t & 15)*4;
      const float* p0 = &x[(((size_t)b*320 + c0+cc)*64 + 2*i)*64 + col4];
      const float* p1 = &x[(((size_t)b*320 + c0+cc)*64 + 2*i+1)*64 + col4];
      float4 a = *(const float4*)p0;
      float4 bb = *(const float4*)p1;
      r0[cc*65+col4+0]=a.x; r0[cc*65+col4+1]=a.y; r0[cc*65+col4+2]=a.z; r0[cc*65+col4+3]=a.w;
      r1[cc*65+col4+0]=bb.x; r1[cc*65+col4+1]=bb.y; r1[cc*65+col4+2]=bb.z; r1[cc*65+col4+3]=bb.w;
    }
    __syncthreads();
    for (int t = tid; t < 2048; t += 256){
      int cl = t & 63, j = t >> 6;
      float a  = r0[cl*65 + 2*j], bv = r0[cl*65 + 2*j + 1];
      float cv = r1[cl*65 + 2*j], dv = r1[cl*65 + 2*j + 1];
      float f0 = 0.5f*(a+bv+cv+dv);
      float f1 = 0.5f*(a+bv-cv-dv);
      float f2 = 0.5f*(a-bv+cv-dv);
      float f3 = 0.5f*(a-bv-cv+dv);
      int l = i*32 + j; int c = c0 + cl;
      xll[((size_t)b*1024 + l)*192 + c] = f0;
      float* hp = &xhigh[((size_t)b*1024 + l)*576 + 3*c];
      hp[0]=f1; hp[1]=f2; hp[2]=f3;
    }
  }
}

// ---------------- transpose x_id (B,128,64,64) channel-major -> A1 pos-major cols 192..320 (lda=320)
__global__ __launch_bounds__(256) void xid_t(const float* __restrict__ x, float* __restrict__ A1){
  __shared__ float l[128][65];
  int hw0 = (blockIdx.x & 63) * 64;
  int b = blockIdx.x >> 6;
  int tid = threadIdx.x;
  for (int t = tid; t < 2048; t += 256){
    int c2 = t >> 4, h4 = (t & 15) * 4;
    float4 v = *(const float4*)&x[((size_t)(b*320 + 192 + c2))*4096 + hw0 + h4];
    l[c2][h4+0]=v.x; l[c2][h4+1]=v.y; l[c2][h4+2]=v.z; l[c2][h4+3]=v.w;
  }
  __syncthreads();
  for (int t = tid; t < 2048; t += 256){
    int hw = t >> 5, c4 = (t & 31) * 4;
    float4 v = make_float4(l[c4+0][hw], l[c4+1][hw], l[c4+2][hw], l[c4+3][hw]);
    *(float4*)&A1[((size_t)b*4096 + hw0 + hw)*320 + 192 + c4] = v;
  }
}

// ---------------- LN over 192 channels per position
__global__ __launch_bounds__(64) void ln192(const float* __restrict__ xll,
                                            const float* __restrict__ g, const float* __restrict__ bt,
                                            float* __restrict__ xln){
  int p = blockIdx.x; int lane = threadIdx.x;
  const float* row = xll + (size_t)p*192;
  float v0 = row[lane], v1 = row[lane+64], v2 = row[lane+128];
  float s = v0+v1+v2, s2 = v0*v0+v1*v1+v2*v2;
  #pragma unroll
  for (int off=32; off; off>>=1){ s += __shfl_xor(s, off, 64); s2 += __shfl_xor(s2, off, 64); }
  float mean = s*(1.f/192.f);
  float var = s2*(1.f/192.f) - mean*mean;
  float rstd = rsqrtf(var + EPSF);
  float* o = xln + (size_t)p*192;
  o[lane]     = (v0-mean)*rstd*g[lane]     + bt[lane];
  o[lane+64]  = (v1-mean)*rstd*g[lane+64]  + bt[lane+64];
  o[lane+128] = (v2-mean)*rstd*g[lane+128] + bt[lane+128];
}

// ---------------- bf16 MFMA GEMM: C[M,N] = A[M,K] * W[N,K]^T, tile 128x64, 4 waves.
// MODE 0: plain pos-major out. MODE 2: A scaled by gate[b][k], BN epilogue.
// MODE 3: BN + residual epilogue, channel-major out (A must be full pos-major, lda=K).
template<int MODE>
__global__ __launch_bounds__(256) void gemm_mfma(
    const float* __restrict__ A, const float* __restrict__ W, float* __restrict__ C,
    int M, int N, int K, int lda,
    const float* __restrict__ gate, const float* __restrict__ bn, const float* __restrict__ xres)
{
  __shared__ unsigned short As[128][40];   // [m][k], +8 pad: 80B rows, 16B-aligned, ~2-way banks
  __shared__ unsigned short Ws[64][40];
  int tid = threadIdx.x;
  int lane = tid & 63, w = tid >> 6;
  int wy = w >> 1, wx = w & 1;
  int frow = lane & 15, fk = (lane >> 4) * 8;
  int m0 = blockIdx.x * 128, n0 = blockIdx.y * 64;
  f32x4 acc[4][2];
  #pragma unroll
  for (int i=0;i<4;i++)
    #pragma unroll
    for (int j=0;j<2;j++) acc[i][j] = (f32x4){0.f,0.f,0.f,0.f};

  for (int k0 = 0; k0 < K; k0 += 32){
    #pragma unroll
    for (int r=0;r<4;r++){
      int fid = tid + 256*r;
      int m = fid >> 3, k4 = (fid & 7)*4;
      float4 v = *(const float4*)&A[(size_t)(m0+m)*lda + k0 + k4];
      if (MODE==2){
        int b = (m0+m) >> 10;
        v.x *= gate[b*576 + k0+k4+0]; v.y *= gate[b*576 + k0+k4+1];
        v.z *= gate[b*576 + k0+k4+2]; v.w *= gate[b*576 + k0+k4+3];
      }
      As[m][k4+0]=f2bf_(v.x); As[m][k4+1]=f2bf_(v.y);
      As[m][k4+2]=f2bf_(v.z); As[m][k4+3]=f2bf_(v.w);
    }
    #pragma unroll
    for (int r=0;r<2;r++){
      int fid = tid + 256*r;
      int n = fid >> 3, k4 = (fid & 7)*4;
      float4 v = *(const float4*)&W[(size_t)(n0+n)*K + k0 + k4];
      Ws[n][k4+0]=f2bf_(v.x); Ws[n][k4+1]=f2bf_(v.y);
      Ws[n][k4+2]=f2bf_(v.z); Ws[n][k4+3]=f2bf_(v.w);
    }
    __syncthreads();
    short8 af[4], bfr[2];
    #pragma unroll
    for (int mt=0;mt<4;mt++) af[mt] = *(const short8*)&As[wy*64 + mt*16 + frow][fk];
    #pragma unroll
    for (int nt=0;nt<2;nt++) bfr[nt] = *(const short8*)&Ws[wx*32 + nt*16 + frow][fk];
    #pragma unroll
    for (int mt=0;mt<4;mt++)
      #pragma unroll
      for (int nt=0;nt<2;nt++)
        acc[mt][nt] = __builtin_amdgcn_mfma_f32_16x16x32_bf16(af[mt], bfr[nt], acc[mt][nt], 0, 0, 0);
    __syncthreads();
  }

  #pragma unroll
  for (int mt=0;mt<4;mt++){
    int row0 = m0 + wy*64 + mt*16 + (lane>>4)*4;
    #pragma unroll
    for (int nt=0;nt<2;nt++){
      int cg = n0 + wx*32 + nt*16 + frow;
      if (MODE==0){
        #pragma unroll
        for (int i=0;i<4;i++) C[(size_t)(row0+i)*N + cg] = acc[mt][nt][i];
      } else if (MODE==2){
        float sc = bn[cg]*rsqrtf(bn[3*N+cg]+EPSF);
        float sh = bn[N+cg] - bn[2*N+cg]*sc;
        #pragma unroll
        for (int i=0;i<4;i++) C[(size_t)(row0+i)*N + cg] = fmaf(acc[mt][nt][i], sc, sh);
      } else {
        float sc = bn[cg]*rsqrtf(bn[3*N+cg]+EPSF);
        float sh = bn[N+cg] - bn[2*N+cg]*sc;
        int b = row0 >> 12, hw0 = row0 & 4095;
        size_t base = ((size_t)(b*320 + cg))*4096 + hw0;
        float4 xr = *(const float4*)&xres[base];
        float4 ov;
        ov.x = xr.x + fmaf(acc[mt][nt][0], sc, sh);
        ov.y = xr.y + fmaf(acc[mt][nt][1], sc, sh);
        ov.z = xr.z + fmaf(acc[mt][nt][2], sc, sh);
        ov.w = xr.w + fmaf(acc[mt][nt][3], sc, sh);
        *(float4*)&C[base] = ov;
      }
    }
  }
}

// ---------------- depthwise 3x3 + bias + SiLU on xm (first 384 cols of xz rows)
__global__ __launch_bounds__(384) void dwconv_silu(const float* __restrict__ xz,
                                                   const float* __restrict__ cw, const float* __restrict__ cb,
                                                   float* __restrict__ xconv){
  int bl = blockIdx.x; int b = bl >> 10, l = bl & 1023;
  int i = l >> 5, j = l & 31;
  int d = threadIdx.x;
  float w[9];
  #pragma unroll
  for (int t=0;t<9;t++) w[t] = cw[d*9+t];
  float acc = cb[d];
  #pragma unroll
  for (int di=-1;di<=1;di++){
    int ii = i+di; if (ii < 0 || ii > 31) continue;
    #pragma unroll
    for (int dj=-1;dj<=1;dj++){
      int jj = j+dj; if (jj < 0 || jj > 31) continue;
      acc += w[(di+1)*3 + (dj+1)] * xz[((size_t)(b*1024 + ii*32 + jj))*768 + d];
    }
  }
  xconv[(size_t)bl*384 + d] = siluf_(acc);
}

// ---------------- x_proj: per (b,dir) GEMM: xdbl[bk][c<44][l] = sum_d xconv[b, map(l), d] * xpw[dir][c][d]
__global__ __launch_bounds__(256) void gemm_xproj(const float* __restrict__ xconv,
                                                  const float* __restrict__ xpw, float* __restrict__ xdbl){
  __shared__ float As[32][128];
  __shared__ float Ws[32][64];
  int tid = threadIdx.x;
  int tx = tid & 15, ty = tid >> 4;
  int m0 = blockIdx.x * 128;
  int bk = blockIdx.z; int b = bk >> 2, dir = bk & 3;
  const float* Wk = xpw + (size_t)dir*44*384;
  float acc[8][4];
  #pragma unroll
  for (int i=0;i<8;i++)
    #pragma unroll
    for (int j=0;j<4;j++) acc[i][j]=0.f;
  for (int k0=0;k0<384;k0+=32){
    #pragma unroll
    for (int r=0;r<4;r++){
      int fid = tid + 256*r;
      int m = fid >> 3, k4 = (fid & 7)*4;
      int l = m0 + m;
      int row = b*1024 + mapdir_(dir, l);
      float4 v = *(const float4*)&xconv[(size_t)row*384 + k0 + k4];
      As[k4+0][m]=v.x; As[k4+1][m]=v.y; As[k4+2][m]=v.z; As[k4+3][m]=v.w;
    }
    #pragma unroll
    for (int r=0;r<2;r++){
      int fid = tid + 256*r;
      int n = fid >> 3, k4 = (fid & 7)*4;
      float4 v = (n < 44) ? *(const float4*)&Wk[(size_t)n*384 + k0 + k4] : make_float4(0.f,0.f,0.f,0.f);
      Ws[k4+0][n]=v.x; Ws[k4+1][n]=v.y; Ws[k4+2][n]=v.z; Ws[k4+3][n]=v.w;
    }
    __syncthreads();
    #pragma unroll
    for (int kk=0;kk<32;kk++){
      float4 a0 = *(float4*)&As[kk][ty*8];
      float4 a1 = *(float4*)&As[kk][ty*8+4];
      float4 bf = *(float4*)&Ws[kk][tx*4];
      float av[8] = {a0.x,a0.y,a0.z,a0.w,a1.x,a1.y,a1.z,a1.w};
      float bv[4] = {bf.x,bf.y,bf.z,bf.w};
      #pragma unroll
      for (int i=0;i<8;i++)
        #pragma unroll
        for (int j=0;j<4;j++)
          acc[i][j] = fmaf(av[i], bv[j], acc[i][j]);
    }
    __syncthreads();
  }
  float* Cb = xdbl + (size_t)bk*44*1024;
  #pragma unroll
  for (int j=0;j<4;j++){
    int c = tx*4 + j;
    if (c < 44){
      float4 o0 = make_float4(acc[0][j],acc[1][j],acc[2][j],acc[3][j]);
      float4 o1 = make_float4(acc[4][j],acc[5][j],acc[6][j],acc[7][j]);
      *(float4*)&Cb[(size_t)c*1024 + m0 + ty*8]     = o0;
      *(float4*)&Cb[(size_t)c*1024 + m0 + ty*8 + 4] = o1;
    }
  }
}

// ---------------- selective scan pass A: chunk summaries, CL=16, 64 chunks.
__global__ __launch_bounds__(256, 4) void scan_chunks(const float* __restrict__ xconv, const float* __restrict__ xdbl,
    const float* __restrict__ dtw_all, const float* __restrict__ dtb_all, const float* __restrict__ alog_all,
    float* __restrict__ Pa, float* __restrict__ Sa){
  __shared__ float xs[28][64];
  int tid = threadIdx.x;
  int dl = tid & 63, cs = tid >> 6;
  int d = blockIdx.x*64 + dl;
  int chunk = blockIdx.y*4 + cs;
  int bk = blockIdx.z; int b = bk >> 2, k = bk & 3;
  const float* xd = xdbl + (size_t)bk*44*1024;
  int L0 = blockIdx.y*64;
  for (int t = tid; t < 28*16; t += 256){
    int c = t >> 4, col = (t & 15) << 2;
    float4 v = *(const float4*)&xd[(size_t)c*1024 + L0 + col];
    *(float4*)&xs[c][col] = v;
  }
  float dtw[12];
  #pragma unroll
  for (int r=0;r<12;r++) dtw[r] = dtw_all[(size_t)(k*384 + d)*12 + r];
  float dtb = dtb_all[k*384 + d];
  float Ar[16];
  #pragma unroll
  for (int n=0;n<16;n++) Ar[n] = -__expf(alog_all[(size_t)(k*384 + d)*16 + n]);
  float h[16], P[16];
  #pragma unroll
  for (int n=0;n<16;n++){ h[n]=0.f; P[n]=1.f; }
  __syncthreads();
  int l0 = chunk*16, c0 = cs*16;
  for (int li=0; li<16; li++){
    int l = l0 + li, col = c0 + li;
    float u = xconv[((size_t)(b*1024 + mapdir_(k, l)))*384 + d];
    float dr = dtb;
    #pragma unroll
    for (int r=0;r<12;r++) dr = fmaf(dtw[r], xs[r][col], dr);
    float delta = softplusf_(dr);
    float du = delta * u;
    #pragma unroll
    for (int n=0;n<16;n++){
      float e = __expf(delta * Ar[n]);
      h[n] = fmaf(e, h[n], du * xs[12+n][col]);
      P[n] *= e;
    }
  }
  size_t base = (((size_t)bk*64 + chunk)*16)*384 + d;
  #pragma unroll
  for (int n=0;n<16;n++){ Pa[base + (size_t)n*384] = P[n]; Sa[base + (size_t)n*384] = h[n]; }
}

// ---------------- pass B: serial chain over 64 chunk states; writes Hinit IN-PLACE into Pa.
__global__ __launch_bounds__(256) void scan_chain(float* __restrict__ Pa, const float* __restrict__ Sa){
  int dl = threadIdx.x & 63, nl = threadIdx.x >> 6;
  int d = blockIdx.x*64 + dl;
  int n = blockIdx.y*4 + nl;
  int bk = blockIdx.z;
  float h = 0.f;
  for (int c=0;c<64;c++){
    size_t idx = (((size_t)bk*64 + c)*16 + n)*384 + d;
    float p = Pa[idx], s = Sa[idx];
    Pa[idx] = h;
    h = fmaf(p, h, s);
  }
}

// ---------------- pass C: re-scan with Hinit (in Pa), emit y. LDS-stages all 44 xdbl rows.
__global__ __launch_bounds__(256, 4) void scan_emit(const float* __restrict__ xconv, const float* __restrict__ xdbl,
    const float* __restrict__ dtw_all, const float* __restrict__ dtb_all, const float* __restrict__ alog_all,
    const float* __restrict__ Ds, const float* __restrict__ Hinit, float* __restrict__ yout){
  __shared__ float xs[44][64];
  int tid = threadIdx.x;
  int dl = tid & 63, cs = tid >> 6;
  int d = blockIdx.x*64 + dl;
  int chunk = blockIdx.y*4 + cs;
  int bk = blockIdx.z; int b = bk >> 2, k = bk & 3;
  const float* xd = xdbl + (size_t)bk*44*1024;
  int L0 = blockIdx.y*64;
  for (int t = tid; t < 44*16; t += 256){
    int c = t >> 4, col = (t & 15) << 2;
    float4 v = *(const float4*)&xd[(size_t)c*1024 + L0 + col];
    *(float4*)&xs[c][col] = v;
  }
  float dtw[12];
  #pragma unroll
  for (int r=0;r<12;r++) dtw[r] = dtw_all[(size_t)(k*384 + d)*12 + r];
  float dtb = dtb_all[k*384 + d];
  float Dv = Ds[k*384 + d];
  float Ar[16];
  #pragma unroll
  for (int n=0;n<16;n++) Ar[n] = -__expf(alog_all[(size_t)(k*384 + d)*16 + n]);
  float h[16];
  size_t hbase = (((size_t)bk*64 + chunk)*16)*384 + d;
  #pragma unroll
  for (int n=0;n<16;n++) h[n] = Hinit[hbase + (size_t)n*384];
  __syncthreads();
  int l0 = chunk*16, c0 = cs*16;
  for (int li=0; li<16; li++){
    int l = l0 + li, col = c0 + li;
    float u = xconv[((size_t)(b*1024 + mapdir_(k, l)))*384 + d];
    float dr = dtb;
    #pragma unroll
    for (int r=0;r<12;r++) dr = fmaf(dtw[r], xs[r][col], dr);
    float delta = softplusf_(dr);
    float du = delta * u;
    float y = Dv * u;
    #pragma unroll
    for (int n=0;n<16;n++){
      float e = __expf(delta * Ar[n]);
      h[n] = fmaf(e, h[n], du * xs[12+n][col]);
      y = fmaf(h[n], xs[28+n][col], y);
    }
    yout[((size_t)bk*1024 + l)*384 + d] = y;
  }
}

// ---------------- merge 4 directions + LN(384) + *silu(z) -> gated pos-major
__global__ __launch_bounds__(64) void merge_ln(const float* __restrict__ ysc, const float* __restrict__ xz,
    const float* __restrict__ ong, const float* __restrict__ onb, float* __restrict__ gated){
  int bl = blockIdx.x; int b = bl >> 10, l = bl & 1023;
  int lane = threadIdx.x;
  int p1 = ((l & 31) << 5) | (l >> 5);
  const float* y0 = ysc + ((size_t)(b*4+0)*1024 + l)*384;
  const float* y1 = ysc + ((size_t)(b*4+1)*1024 + p1)*384;
  const float* y2 = ysc + ((size_t)(b*4+2)*1024 + (1023-l))*384;
  const float* y3 = ysc + ((size_t)(b*4+3)*1024 + (1023-p1))*384;
  float v[6]; float s = 0.f, s2 = 0.f;
  #pragma unroll
  for (int r=0;r<6;r++){
    int d = lane + 64*r;
    float t = y0[d] + y1[d] + y2[d] + y3[d];
    v[r] = t; s += t; s2 += t*t;
  }
  #pragma unroll
  for (int off=32; off; off>>=1){ s += __shfl_xor(s, off, 64); s2 += __shfl_xor(s2, off, 64); }
  float mean = s*(1.f/384.f);
  float var = s2*(1.f/384.f) - mean*mean;
  float rstd = rsqrtf(var + EPSF);
  const float* zrow = xz + (size_t)bl*768 + 384;
  float* grow = gated + (size_t)bl*384;
  #pragma unroll
  for (int r=0;r<6;r++){
    int d = lane + 64*r;
    float z = zrow[d];
    grow[d] = ((v[r]-mean)*rstd*ong[d] + onb[d]) * siluf_(z);
  }
}

// ---------------- high path depthwise 3x3 + BN (+ReLU)
template<int RELU>
__global__ __launch_bounds__(576) void dwconv_bn(const float* __restrict__ hin,
    const float* __restrict__ dw, const float* __restrict__ bn, float* __restrict__ hout){
  int bl = blockIdx.x; int b = bl >> 10, l = bl & 1023;
  int i = l >> 5, j = l & 31;
  int d = threadIdx.x;
  float w[9];
  #pragma unroll
  for (int t=0;t<9;t++) w[t] = dw[d*9+t];
  float acc = 0.f;
  #pragma unroll
  for (int di=-1;di<=1;di++){
    int ii = i+di; if (ii < 0 || ii > 31) continue;
    #pragma unroll
    for (int dj=-1;dj<=1;dj++){
      int jj = j+dj; if (jj < 0 || jj > 31) continue;
      acc += w[(di+1)*3 + (dj+1)] * hin[((size_t)(b*1024 + ii*32 + jj))*576 + d];
    }
  }
  float sc = bn[d] * rsqrtf(bn[3*576+d] + EPSF);
  float vv = (acc - bn[2*576+d])*sc + bn[576+d];
  if (RELU) vv = fmaxf(vv, 0.f);
  hout[(size_t)bl*576 + d] = vv;
}

// ---------------- spatial mean of h2 per (b, d)
__global__ __launch_bounds__(256) void mean576(const float* __restrict__ h2, float* __restrict__ smean){
  __shared__ float red[256];
  int dg = blockIdx.x, b = blockIdx.y;
  int dl = threadIdx.x & 63, lq = threadIdx.x >> 6;
  int d = dg*64 + dl;
  float ps = 0.f;
  for (int l = lq; l < 1024; l += 4)
    ps += h2[((size_t)(b*1024 + l))*576 + d];
  red[threadIdx.x] = ps;
  __syncthreads();
  if (threadIdx.x < 64){
    float ssum = red[threadIdx.x] + red[threadIdx.x+64] + red[threadIdx.x+128] + red[threadIdx.x+192];
    smean[b*576 + dg*64 + threadIdx.x] = ssum * (1.f/1024.f);
  }
}

// ---------------- SE gate
__global__ __launch_bounds__(256) void se_gate(const float* __restrict__ smean,
    const float* __restrict__ rw, const float* __restrict__ rb,
    const float* __restrict__ ew, const float* __restrict__ eb, float* __restrict__ gate4){
  __shared__ float s_ld[576];
  __shared__ float r_ld[144];
  int b = blockIdx.x, t = threadIdx.x;
  for (int c=t; c<576; c+=256) s_ld[c] = smean[b*576+c];
  __syncthreads();
  if (t < 144){
    float a = rb[t];
    for (int c=0;c<576;c++) a = fmaf(rw[(size_t)t*576+c], s_ld[c], a);
    r_ld[t] = fmaxf(a, 0.f);
  }
  __syncthreads();
  for (int d=t; d<576; d+=256){
    float a = eb[d];
    for (int j=0;j<144;j++) a = fmaf(ew[(size_t)d*144+j], r_ld[j], a);
    gate4[b*576+d] = sigmoidf_(a);
  }
}

// ---------------- wavelet reconstruct into A1 pos-major cols 0..192 (lda=320)
__global__ __launch_bounds__(192) void recon(const float* __restrict__ xllout, const float* __restrict__ h2o,
                                             float* __restrict__ A1){
  int bl = blockIdx.x; int b = bl >> 10, lr = bl & 1023;
  int c = threadIdx.x;
  int i = lr >> 5, j = lr & 31;
  float f0 = xllout[(size_t)bl*192 + c];
  const float* hp = &h2o[(size_t)bl*576 + 3*c];
  float f1 = hp[0], f2 = hp[1], f3 = hp[2];
  float v00 = 0.5f*(f0 - f1 - f2 + f3);
  float v01 = 0.5f*(f0 - f1 + f2 - f3);
  float v10 = 0.5f*(f0 + f1 - f2 - f3);
  float v11 = 0.5f*(f0 + f1 + f2 + f3);
  size_t base = ((size_t)b*4096 + (size_t)(2*i)*64 + 2*j)*320 + c;
  A1[base]            = v00;
  A1[base + 320]      = v01;
  A1[base + 64*320]   = v10;
  A1[base + 65*320]   = v11;
}

extern "C" void kernel_launch(void* const* d_in, const int* in_sizes, int n_in,
                              void* d_out, int out_size, void* d_ws, size_t ws_size,
                              hipStream_t stream) {
  const float* x         = (const float*)d_in[0];
  const float* in_proj_w = (const float*)d_in[1];
  const float* conv_w    = (const float*)d_in[2];
  const float* conv_b    = (const float*)d_in[3];
  const float* x_proj_w  = (const float*)d_in[4];
  const float* dt_proj_w = (const float*)d_in[5];
  const float* dt_proj_b = (const float*)d_in[6];
  const float* A_logs    = (const float*)d_in[7];
  const float* Dsp       = (const float*)d_in[8];
  const float* out_norm_g= (const float*)d_in[9];
  const float* out_norm_b= (const float*)d_in[10];
  const float* out_proj_w= (const float*)d_in[11];
  const float* norm_g    = (const float*)d_in[12];
  const float* norm_b    = (const float*)d_in[13];
  const float* lp_dw1_w  = (const float*)d_in[14];
  const float* lp_bn1    = (const float*)d_in[15];
  const float* lp_dw2_w  = (const float*)d_in[16];
  const float* lp_bn2    = (const float*)d_in[17];
  const float* se_rw     = (const float*)d_in[18];
  const float* se_rb     = (const float*)d_in[19];
  const float* se_ew     = (const float*)d_in[20];
  const float* se_eb     = (const float*)d_in[21];
  const float* lp_pw_w   = (const float*)d_in[22];
  const float* lp_bn3    = (const float*)d_in[23];
  const float* proj_w    = (const float*)d_in[24];
  const float* proj_bn   = (const float*)d_in[25];
  float* out = (float*)d_out;
  float* ws = (float*)d_ws;

  // time-phased workspace plan (floats) — total 21,959,168 floats = 87.8 MB
  float* xhigh = ws;                   // 2359296  : wav_dec -> dwconv_bn1
  float* xz    = xhigh + 2359296;      // 3145728  : in_proj -> merge_ln      (later h2)
  float* xconv = xz + 3145728;         // 1572864  : dwconv_silu -> scan C    (later gated)
  float* xdbl  = xconv + 1572864;      // 720896   : xproj -> scan C
  float* Pa    = xdbl + 720896;        // 6291456  : scanA -> chain(in-place Hinit) -> scanC  (later h1, h2o)
  float* Sa    = Pa + 6291456;         // 6291456  : scanA -> chain -> yscan -> merge_ln; then A1 (16384*320)
  float* xll   = Sa + 6291456;         // 786432   : wav_dec -> ln192         (later xllout)
  float* xln   = xll + 786432;         // 786432   : ln192 -> in_proj
  float* smean = xln + 786432;         // 2304
  float* gate4 = smean + 2304;         // 2304
  float* Hinit = Pa;       // chain overwrites Pa in place with per-chunk init states
  float* yscan = Sa;       // pass C output (Sa dead after chain)
  float* gated = xconv;    // merge_ln output (xconv dead after pass C)
  float* xllout= xll;      // out_proj output (xll dead after ln192)
  float* h1    = Pa;       // dwconv_bn1 output (Pa dead after pass C)
  float* h2    = xz;       // dwconv_bn2 output (xz dead after merge_ln)
  float* h2o   = Pa;       // pw gemm output (h1 dead after dwconv_bn2)
  float* A1    = Sa;       // recon + xid_t output (yscan dead after merge_ln); 5,242,880 floats

  wav_dec<<<dim3(128), dim3(256), 0, stream>>>(x, xll, xhigh);
  ln192<<<dim3(4096), dim3(64), 0, stream>>>(xll, norm_g, norm_b, xln);
  gemm_mfma<0><<<dim3(32,12), dim3(256), 0, stream>>>(xln, in_proj_w, xz, 4096, 768, 192, 192,
                                                      nullptr, nullptr, nullptr);
  dwconv_silu<<<dim3(4096), dim3(384), 0, stream>>>(xz, conv_w, conv_b, xconv);
  gemm_xproj<<<dim3(8,1,16), dim3(256), 0, stream>>>(xconv, x_proj_w, xdbl);
  scan_chunks<<<dim3(6,16,16), dim3(256), 0, stream>>>(xconv, xdbl, dt_proj_w, dt_proj_b, A_logs, Pa, Sa);
  scan_chain<<<dim3(6,4,16), dim3(256), 0, stream>>>(Pa, Sa);
  scan_emit<<<dim3(6,16,16), dim3(256), 0, stream>>>(xconv, xdbl, dt_proj_w, dt_proj_b, A_logs, Dsp, Hinit, yscan);
  merge_ln<<<dim3(4096), dim3(64), 0, stream>>>(yscan, xz, out_norm_g, out_norm_b, gated);
  gemm_mfma<0><<<dim3(32,3), dim3(256), 0, stream>>>(gated, out_proj_w, xllout, 4096, 192, 384, 384,
                                                     nullptr, nullptr, nullptr);
  xid_t<<<dim3(256), dim3(256), 0, stream>>>(x, A1);
  dwconv_bn<1><<<dim3(4096), dim3(576), 0, stream>>>(xhigh, lp_dw1_w, lp_bn1, h1);
  dwconv_bn<0><<<dim3(4096), dim3(576), 0, stream>>>(h1, lp_dw2_w, lp_bn2, h2);
  mean576<<<dim3(9,4), dim3(256), 0, stream>>>(h2, smean);
  se_gate<<<dim3(4), dim3(256), 0, stream>>>(smean, se_rw, se_rb, se_ew, se_eb, gate4);
  gemm_mfma<2><<<dim3(32,9), dim3(256), 0, stream>>>(h2, lp_pw_w, h2o, 4096, 576, 576, 576,
                                                     gate4, lp_bn3, nullptr);
  recon<<<dim3(4096), dim3(192), 0, stream>>>(xllout, h2o, A1);
  gemm_mfma<3><<<dim3(128,5), dim3(256), 0, stream>>>(A1, proj_w, out, 16384, 320, 320, 320,
                                                      nullptr, proj_bn, x);
}

// Round 7
// 482.710 us; speedup vs baseline: 1.4793x; 1.1295x over previous
//
#include <hip/hip_runtime.h>
#include <cstdint>

#define EPSF 1e-5f

typedef __attribute__((ext_vector_type(8))) short short8;
typedef __attribute__((ext_vector_type(4))) float f32x4;

__device__ __forceinline__ float sigmoidf_(float x){ return 1.f/(1.f+__expf(-x)); }
__device__ __forceinline__ float siluf_(float x){ return x*sigmoidf_(x); }
__device__ __forceinline__ float softplusf_(float x){ return fmaxf(x,0.f) + log1pf(__expf(-fabsf(x))); }
__device__ __forceinline__ int mapdir_(int dir, int l){
  int lt = (dir & 2) ? (1023 - l) : l;
  return (dir & 1) ? (((lt & 31) << 5) | (lt >> 5)) : lt;
}
__device__ __forceinline__ unsigned short f2bf_(float f){
  unsigned int u = __float_as_uint(f);
  u = (u + 0x7FFFu + ((u >> 16) & 1u)) >> 16;
  return (unsigned short)u;
}

// ---------------- wavelet decompose: x[:,0:192] (B,192,64,64) -> xll pos-major (B*1024,192),
// ---------------- xhigh pos-major (B*1024,576) with hc = 3*c + (f-1)
__global__ __launch_bounds__(256) void wav_dec(const float* __restrict__ x,
                                               float* __restrict__ xll, float* __restrict__ xhigh){
  int b = blockIdx.x >> 5, i = blockIdx.x & 31;
  __shared__ float r0[64*65];
  __shared__ float r1[64*65];
  int tid = threadIdx.x;
  for (int c0 = 0; c0 < 192; c0 += 64){
    if (c0) __syncthreads();
    for (int t = tid; t < 1024; t += 256){
      int cc = t >> 4, col4 = (t & 15)*4;
      const float* p0 = &x[(((size_t)b*320 + c0+cc)*64 + 2*i)*64 + col4];
      const float* p1 = &x[(((size_t)b*320 + c0+cc)*64 + 2*i+1)*64 + col4];
      float4 a = *(const float4*)p0;
      float4 bb = *(const float4*)p1;
      r0[cc*65+col4+0]=a.x; r0[cc*65+col4+1]=a.y; r0[cc*65+col4+2]=a.z; r0[cc*65+col4+3]=a.w;
      r1[cc*65+col4+0]=bb.x; r1[cc*65+col4+1]=bb.y; r1[cc*65+col4+2]=bb.z; r1[cc*65+col4+3]=bb.w;
    }
    __syncthreads();
    for (int t = tid; t < 2048; t += 256){
      int cl = t & 63, j = t >> 6;
      float a  = r0[cl*65 + 2*j], bv = r0[cl*65 + 2*j + 1];
      float cv = r1[cl*65 + 2*j], dv = r1[cl*65 + 2*j + 1];
      float f0 = 0.5f*(a+bv+cv+dv);
      float f1 = 0.5f*(a+bv-cv-dv);
      float f2 = 0.5f*(a-bv+cv-dv);
      float f3 = 0.5f*(a-bv-cv+dv);
      int l = i*32 + j; int c = c0 + cl;
      xll[((size_t)b*1024 + l)*192 + c] = f0;
      float* hp = &xhigh[((size_t)b*1024 + l)*576 + 3*c];
      hp[0]=f1; hp[1]=f2; hp[2]=f3;
    }
  }
}

// ---------------- transpose x_id (B,128,64,64) channel-major -> A1 pos-major cols 192..320 (lda=320)
__global__ __launch_bounds__(256) void xid_t(const float* __restrict__ x, float* __restrict__ A1){
  __shared__ float l[128][65];
  int hw0 = (blockIdx.x & 63) * 64;
  int b = blockIdx.x >> 6;
  int tid = threadIdx.x;
  for (int t = tid; t < 2048; t += 256){
    int c2 = t >> 4, h4 = (t & 15) * 4;
    float4 v = *(const float4*)&x[((size_t)(b*320 + 192 + c2))*4096 + hw0 + h4];
    l[c2][h4+0]=v.x; l[c2][h4+1]=v.y; l[c2][h4+2]=v.z; l[c2][h4+3]=v.w;
  }
  __syncthreads();
  for (int t = tid; t < 2048; t += 256){
    int hw = t >> 5, c4 = (t & 31) * 4;
    float4 v = make_float4(l[c4+0][hw], l[c4+1][hw], l[c4+2][hw], l[c4+3][hw]);
    *(float4*)&A1[((size_t)b*4096 + hw0 + hw)*320 + 192 + c4] = v;
  }
}

// ---------------- LN over 192 channels per position
__global__ __launch_bounds__(64) void ln192(const float* __restrict__ xll,
                                            const float* __restrict__ g, const float* __restrict__ bt,
                                            float* __restrict__ xln){
  int p = blockIdx.x; int lane = threadIdx.x;
  const float* row = xll + (size_t)p*192;
  float v0 = row[lane], v1 = row[lane+64], v2 = row[lane+128];
  float s = v0+v1+v2, s2 = v0*v0+v1*v1+v2*v2;
  #pragma unroll
  for (int off=32; off; off>>=1){ s += __shfl_xor(s, off, 64); s2 += __shfl_xor(s2, off, 64); }
  float mean = s*(1.f/192.f);
  float var = s2*(1.f/192.f) - mean*mean;
  float rstd = rsqrtf(var + EPSF);
  float* o = xln + (size_t)p*192;
  o[lane]     = (v0-mean)*rstd*g[lane]     + bt[lane];
  o[lane+64]  = (v1-mean)*rstd*g[lane+64]  + bt[lane+64];
  o[lane+128] = (v2-mean)*rstd*g[lane+128] + bt[lane+128];
}

// ---------------- bf16 MFMA GEMM: C[M,N] = A[M,K] * W[N,K]^T, tile 128x64, 4 waves.
// MODE 0: plain pos-major out. MODE 2: A scaled by gate[b][k], BN epilogue.
// MODE 3: BN + residual epilogue, channel-major out (A must be full pos-major, lda=K).
template<int MODE>
__global__ __launch_bounds__(256) void gemm_mfma(
    const float* __restrict__ A, const float* __restrict__ W, float* __restrict__ C,
    int M, int N, int K, int lda,
    const float* __restrict__ gate, const float* __restrict__ bn, const float* __restrict__ xres)
{
  __shared__ unsigned short As[128][40];   // [m][k], +8 pad: 80B rows, 16B-aligned, ~2-way banks
  __shared__ unsigned short Ws[64][40];
  int tid = threadIdx.x;
  int lane = tid & 63, w = tid >> 6;
  int wy = w >> 1, wx = w & 1;
  int frow = lane & 15, fk = (lane >> 4) * 8;
  int m0 = blockIdx.x * 128, n0 = blockIdx.y * 64;
  f32x4 acc[4][2];
  #pragma unroll
  for (int i=0;i<4;i++)
    #pragma unroll
    for (int j=0;j<2;j++) acc[i][j] = (f32x4){0.f,0.f,0.f,0.f};

  for (int k0 = 0; k0 < K; k0 += 32){
    #pragma unroll
    for (int r=0;r<4;r++){
      int fid = tid + 256*r;
      int m = fid >> 3, k4 = (fid & 7)*4;
      float4 v = *(const float4*)&A[(size_t)(m0+m)*lda + k0 + k4];
      if (MODE==2){
        int b = (m0+m) >> 10;
        v.x *= gate[b*576 + k0+k4+0]; v.y *= gate[b*576 + k0+k4+1];
        v.z *= gate[b*576 + k0+k4+2]; v.w *= gate[b*576 + k0+k4+3];
      }
      As[m][k4+0]=f2bf_(v.x); As[m][k4+1]=f2bf_(v.y);
      As[m][k4+2]=f2bf_(v.z); As[m][k4+3]=f2bf_(v.w);
    }
    #pragma unroll
    for (int r=0;r<2;r++){
      int fid = tid + 256*r;
      int n = fid >> 3, k4 = (fid & 7)*4;
      float4 v = *(const float4*)&W[(size_t)(n0+n)*K + k0 + k4];
      Ws[n][k4+0]=f2bf_(v.x); Ws[n][k4+1]=f2bf_(v.y);
      Ws[n][k4+2]=f2bf_(v.z); Ws[n][k4+3]=f2bf_(v.w);
    }
    __syncthreads();
    short8 af[4], bfr[2];
    #pragma unroll
    for (int mt=0;mt<4;mt++) af[mt] = *(const short8*)&As[wy*64 + mt*16 + frow][fk];
    #pragma unroll
    for (int nt=0;nt<2;nt++) bfr[nt] = *(const short8*)&Ws[wx*32 + nt*16 + frow][fk];
    #pragma unroll
    for (int mt=0;mt<4;mt++)
      #pragma unroll
      for (int nt=0;nt<2;nt++)
        acc[mt][nt] = __builtin_amdgcn_mfma_f32_16x16x32_bf16(af[mt], bfr[nt], acc[mt][nt], 0, 0, 0);
    __syncthreads();
  }

  #pragma unroll
  for (int mt=0;mt<4;mt++){
    int row0 = m0 + wy*64 + mt*16 + (lane>>4)*4;
    #pragma unroll
    for (int nt=0;nt<2;nt++){
      int cg = n0 + wx*32 + nt*16 + frow;
      if (MODE==0){
        #pragma unroll
        for (int i=0;i<4;i++) C[(size_t)(row0+i)*N + cg] = acc[mt][nt][i];
      } else if (MODE==2){
        float sc = bn[cg]*rsqrtf(bn[3*N+cg]+EPSF);
        float sh = bn[N+cg] - bn[2*N+cg]*sc;
        #pragma unroll
        for (int i=0;i<4;i++) C[(size_t)(row0+i)*N + cg] = fmaf(acc[mt][nt][i], sc, sh);
      } else {
        float sc = bn[cg]*rsqrtf(bn[3*N+cg]+EPSF);
        float sh = bn[N+cg] - bn[2*N+cg]*sc;
        int b = row0 >> 12, hw0 = row0 & 4095;
        size_t base = ((size_t)(b*320 + cg))*4096 + hw0;
        float4 xr = *(const float4*)&xres[base];
        float4 ov;
        ov.x = xr.x + fmaf(acc[mt][nt][0], sc, sh);
        ov.y = xr.y + fmaf(acc[mt][nt][1], sc, sh);
        ov.z = xr.z + fmaf(acc[mt][nt][2], sc, sh);
        ov.w = xr.w + fmaf(acc[mt][nt][3], sc, sh);
        *(float4*)&C[base] = ov;
      }
    }
  }
}

// ---------------- depthwise 3x3 + bias + SiLU on xm (first 384 cols of xz rows)
__global__ __launch_bounds__(384) void dwconv_silu(const float* __restrict__ xz,
                                                   const float* __restrict__ cw, const float* __restrict__ cb,
                                                   float* __restrict__ xconv){
  int bl = blockIdx.x; int b = bl >> 10, l = bl & 1023;
  int i = l >> 5, j = l & 31;
  int d = threadIdx.x;
  float w[9];
  #pragma unroll
  for (int t=0;t<9;t++) w[t] = cw[d*9+t];
  float acc = cb[d];
  #pragma unroll
  for (int di=-1;di<=1;di++){
    int ii = i+di; if (ii < 0 || ii > 31) continue;
    #pragma unroll
    for (int dj=-1;dj<=1;dj++){
      int jj = j+dj; if (jj < 0 || jj > 31) continue;
      acc += w[(di+1)*3 + (dj+1)] * xz[((size_t)(b*1024 + ii*32 + jj))*768 + d];
    }
  }
  xconv[(size_t)bl*384 + d] = siluf_(acc);
}

// ---------------- x_proj: per (b,dir) GEMM: xdbl[bk][c<44][l] = sum_d xconv[b, map(l), d] * xpw[dir][c][d]
__global__ __launch_bounds__(256) void gemm_xproj(const float* __restrict__ xconv,
                                                  const float* __restrict__ xpw, float* __restrict__ xdbl){
  __shared__ float As[32][128];
  __shared__ float Ws[32][64];
  int tid = threadIdx.x;
  int tx = tid & 15, ty = tid >> 4;
  int m0 = blockIdx.x * 128;
  int bk = blockIdx.z; int b = bk >> 2, dir = bk & 3;
  const float* Wk = xpw + (size_t)dir*44*384;
  float acc[8][4];
  #pragma unroll
  for (int i=0;i<8;i++)
    #pragma unroll
    for (int j=0;j<4;j++) acc[i][j]=0.f;
  for (int k0=0;k0<384;k0+=32){
    #pragma unroll
    for (int r=0;r<4;r++){
      int fid = tid + 256*r;
      int m = fid >> 3, k4 = (fid & 7)*4;
      int l = m0 + m;
      int row = b*1024 + mapdir_(dir, l);
      float4 v = *(const float4*)&xconv[(size_t)row*384 + k0 + k4];
      As[k4+0][m]=v.x; As[k4+1][m]=v.y; As[k4+2][m]=v.z; As[k4+3][m]=v.w;
    }
    #pragma unroll
    for (int r=0;r<2;r++){
      int fid = tid + 256*r;
      int n = fid >> 3, k4 = (fid & 7)*4;
      float4 v = (n < 44) ? *(const float4*)&Wk[(size_t)n*384 + k0 + k4] : make_float4(0.f,0.f,0.f,0.f);
      Ws[k4+0][n]=v.x; Ws[k4+1][n]=v.y; Ws[k4+2][n]=v.z; Ws[k4+3][n]=v.w;
    }
    __syncthreads();
    #pragma unroll
    for (int kk=0;kk<32;kk++){
      float4 a0 = *(float4*)&As[kk][ty*8];
      float4 a1 = *(float4*)&As[kk][ty*8+4];
      float4 bf = *(float4*)&Ws[kk][tx*4];
      float av[8] = {a0.x,a0.y,a0.z,a0.w,a1.x,a1.y,a1.z,a1.w};
      float bv[4] = {bf.x,bf.y,bf.z,bf.w};
      #pragma unroll
      for (int i=0;i<8;i++)
        #pragma unroll
        for (int j=0;j<4;j++)
          acc[i][j] = fmaf(av[i], bv[j], acc[i][j]);
    }
    __syncthreads();
  }
  float* Cb = xdbl + (size_t)bk*44*1024;
  #pragma unroll
  for (int j=0;j<4;j++){
    int c = tx*4 + j;
    if (c < 44){
      float4 o0 = make_float4(acc[0][j],acc[1][j],acc[2][j],acc[3][j]);
      float4 o1 = make_float4(acc[4][j],acc[5][j],acc[6][j],acc[7][j]);
      *(float4*)&Cb[(size_t)c*1024 + m0 + ty*8]     = o0;
      *(float4*)&Cb[(size_t)c*1024 + m0 + ty*8 + 4] = o1;
    }
  }
}

// ---------------- selective scan pass A: chunk summaries, CL=16, 64 chunks.
__global__ __launch_bounds__(256, 4) void scan_chunks(const float* __restrict__ xconv, const float* __restrict__ xdbl,
    const float* __restrict__ dtw_all, const float* __restrict__ dtb_all, const float* __restrict__ alog_all,
    float* __restrict__ Pa, float* __restrict__ Sa){
  __shared__ float xs[28][64];
  int tid = threadIdx.x;
  int dl = tid & 63, cs = tid >> 6;
  int d = blockIdx.x*64 + dl;
  int chunk = blockIdx.y*4 + cs;
  int bk = blockIdx.z; int b = bk >> 2, k = bk & 3;
  const float* xd = xdbl + (size_t)bk*44*1024;
  int L0 = blockIdx.y*64;
  for (int t = tid; t < 28*16; t += 256){
    int c = t >> 4, col = (t & 15) << 2;
    float4 v = *(const float4*)&xd[(size_t)c*1024 + L0 + col];
    *(float4*)&xs[c][col] = v;
  }
  float dtw[12];
  #pragma unroll
  for (int r=0;r<12;r++) dtw[r] = dtw_all[(size_t)(k*384 + d)*12 + r];
  float dtb = dtb_all[k*384 + d];
  float Ar[16];
  #pragma unroll
  for (int n=0;n<16;n++) Ar[n] = -__expf(alog_all[(size_t)(k*384 + d)*16 + n]);
  float h[16], P[16];
  #pragma unroll
  for (int n=0;n<16;n++){ h[n]=0.f; P[n]=1.f; }
  __syncthreads();
  int l0 = chunk*16, c0 = cs*16;
  for (int li=0; li<16; li++){
    int l = l0 + li, col = c0 + li;
    float u = xconv[((size_t)(b*1024 + mapdir_(k, l)))*384 + d];
    float dr = dtb;
    #pragma unroll
    for (int r=0;r<12;r++) dr = fmaf(dtw[r], xs[r][col], dr);
    float delta = softplusf_(dr);
    float du = delta * u;
    #pragma unroll
    for (int n=0;n<16;n++){
      float e = __expf(delta * Ar[n]);
      h[n] = fmaf(e, h[n], du * xs[12+n][col]);
      P[n] *= e;
    }
  }
  size_t base = (((size_t)bk*64 + chunk)*16)*384 + d;
  #pragma unroll
  for (int n=0;n<16;n++){ Pa[base + (size_t)n*384] = P[n]; Sa[base + (size_t)n*384] = h[n]; }
}

// ---------------- pass B: serial chain over 64 chunk states; writes Hinit IN-PLACE into Pa.
__global__ __launch_bounds__(256) void scan_chain(float* __restrict__ Pa, const float* __restrict__ Sa){
  int dl = threadIdx.x & 63, nl = threadIdx.x >> 6;
  int d = blockIdx.x*64 + dl;
  int n = blockIdx.y*4 + nl;
  int bk = blockIdx.z;
  float h = 0.f;
  for (int c=0;c<64;c++){
    size_t idx = (((size_t)bk*64 + c)*16 + n)*384 + d;
    float p = Pa[idx], s = Sa[idx];
    Pa[idx] = h;
    h = fmaf(p, h, s);
  }
}

// ---------------- pass C: re-scan with Hinit (in Pa), emit y. LDS-stages all 44 xdbl rows.
__global__ __launch_bounds__(256, 4) void scan_emit(const float* __restrict__ xconv, const float* __restrict__ xdbl,
    const float* __restrict__ dtw_all, const float* __restrict__ dtb_all, const float* __restrict__ alog_all,
    const float* __restrict__ Ds, const float* __restrict__ Hinit, float* __restrict__ yout){
  __shared__ float xs[44][64];
  int tid = threadIdx.x;
  int dl = tid & 63, cs = tid >> 6;
  int d = blockIdx.x*64 + dl;
  int chunk = blockIdx.y*4 + cs;
  int bk = blockIdx.z; int b = bk >> 2, k = bk & 3;
  const float* xd = xdbl + (size_t)bk*44*1024;
  int L0 = blockIdx.y*64;
  for (int t = tid; t < 44*16; t += 256){
    int c = t >> 4, col = (t & 15) << 2;
    float4 v = *(const float4*)&xd[(size_t)c*1024 + L0 + col];
    *(float4*)&xs[c][col] = v;
  }
  float dtw[12];
  #pragma unroll
  for (int r=0;r<12;r++) dtw[r] = dtw_all[(size_t)(k*384 + d)*12 + r];
  float dtb = dtb_all[k*384 + d];
  float Dv = Ds[k*384 + d];
  float Ar[16];
  #pragma unroll
  for (int n=0;n<16;n++) Ar[n] = -__expf(alog_all[(size_t)(k*384 + d)*16 + n]);
  float h[16];
  size_t hbase = (((size_t)bk*64 + chunk)*16)*384 + d;
  #pragma unroll
  for (int n=0;n<16;n++) h[n] = Hinit[hbase + (size_t)n*384];
  __syncthreads();
  int l0 = chunk*16, c0 = cs*16;
  for (int li=0; li<16; li++){
    int l = l0 + li, col = c0 + li;
    float u = xconv[((size_t)(b*1024 + mapdir_(k, l)))*384 + d];
    float dr = dtb;
    #pragma unroll
    for (int r=0;r<12;r++) dr = fmaf(dtw[r], xs[r][col], dr);
    float delta = softplusf_(dr);
    float du = delta * u;
    float y = Dv * u;
    #pragma unroll
    for (int n=0;n<16;n++){
      float e = __expf(delta * Ar[n]);
      h[n] = fmaf(e, h[n], du * xs[12+n][col]);
      y = fmaf(h[n], xs[28+n][col], y);
    }
    yout[((size_t)bk*1024 + l)*384 + d] = y;
  }
}

// ---------------- merge 4 directions + LN(384) + *silu(z) -> gated pos-major
__global__ __launch_bounds__(64) void merge_ln(const float* __restrict__ ysc, const float* __restrict__ xz,
    const float* __restrict__ ong, const float* __restrict__ onb, float* __restrict__ gated){
  int bl = blockIdx.x; int b = bl >> 10, l = bl & 1023;
  int lane = threadIdx.x;
  int p1 = ((l & 31) << 5) | (l >> 5);
  const float* y0 = ysc + ((size_t)(b*4+0)*1024 + l)*384;
  const float* y1 = ysc + ((size_t)(b*4+1)*1024 + p1)*384;
  const float* y2 = ysc + ((size_t)(b*4+2)*1024 + (1023-l))*384;
  const float* y3 = ysc + ((size_t)(b*4+3)*1024 + (1023-p1))*384;
  float v[6]; float s = 0.f, s2 = 0.f;
  #pragma unroll
  for (int r=0;r<6;r++){
    int d = lane + 64*r;
    float t = y0[d] + y1[d] + y2[d] + y3[d];
    v[r] = t; s += t; s2 += t*t;
  }
  #pragma unroll
  for (int off=32; off; off>>=1){ s += __shfl_xor(s, off, 64); s2 += __shfl_xor(s2, off, 64); }
  float mean = s*(1.f/384.f);
  float var = s2*(1.f/384.f) - mean*mean;
  float rstd = rsqrtf(var + EPSF);
  const float* zrow = xz + (size_t)bl*768 + 384;
  float* grow = gated + (size_t)bl*384;
  #pragma unroll
  for (int r=0;r<6;r++){
    int d = lane + 64*r;
    float z = zrow[d];
    grow[d] = ((v[r]-mean)*rstd*ong[d] + onb[d]) * siluf_(z);
  }
}

// ---------------- high path depthwise 3x3 + BN (+ReLU)
template<int RELU>
__global__ __launch_bounds__(576) void dwconv_bn(const float* __restrict__ hin,
    const float* __restrict__ dw, const float* __restrict__ bn, float* __restrict__ hout){
  int bl = blockIdx.x; int b = bl >> 10, l = bl & 1023;
  int i = l >> 5, j = l & 31;
  int d = threadIdx.x;
  float w[9];
  #pragma unroll
  for (int t=0;t<9;t++) w[t] = dw[d*9+t];
  float acc = 0.f;
  #pragma unroll
  for (int di=-1;di<=1;di++){
    int ii = i+di; if (ii < 0 || ii > 31) continue;
    #pragma unroll
    for (int dj=-1;dj<=1;dj++){
      int jj = j+dj; if (jj < 0 || jj > 31) continue;
      acc += w[(di+1)*3 + (dj+1)] * hin[((size_t)(b*1024 + ii*32 + jj))*576 + d];
    }
  }
  float sc = bn[d] * rsqrtf(bn[3*576+d] + EPSF);
  float vv = (acc - bn[2*576+d])*sc + bn[576+d];
  if (RELU) vv = fmaxf(vv, 0.f);
  hout[(size_t)bl*576 + d] = vv;
}

// ---------------- spatial partial sums of h2: grid (9, 4, 32), each block sums 32 positions
__global__ __launch_bounds__(256) void mean576p(const float* __restrict__ h2, float* __restrict__ partials){
  __shared__ float red[256];
  int dg = blockIdx.x, b = blockIdx.y, ch = blockIdx.z;
  int dl = threadIdx.x & 63, lq = threadIdx.x >> 6;
  int d = dg*64 + dl;
  int l0 = ch*32;
  float ps = 0.f;
  #pragma unroll
  for (int li = 0; li < 8; li++){
    int l = l0 + lq + li*4;
    ps += h2[((size_t)(b*1024 + l))*576 + d];
  }
  red[threadIdx.x] = ps;
  __syncthreads();
  if (threadIdx.x < 64){
    float ssum = red[threadIdx.x] + red[threadIdx.x+64] + red[threadIdx.x+128] + red[threadIdx.x+192];
    partials[((size_t)(b*32 + ch))*576 + dg*64 + threadIdx.x] = ssum;
  }
}

// ---------------- SE gate (sums 32 partials per channel, then two tiny GEMVs)
__global__ __launch_bounds__(256) void se_gate(const float* __restrict__ partials,
    const float* __restrict__ rw, const float* __restrict__ rb,
    const float* __restrict__ ew, const float* __restrict__ eb, float* __restrict__ gate4){
  __shared__ float s_ld[576];
  __shared__ float r_ld[144];
  int b = blockIdx.x, t = threadIdx.x;
  for (int c=t; c<576; c+=256){
    float s = 0.f;
    #pragma unroll
    for (int ch=0; ch<32; ch++) s += partials[((size_t)(b*32 + ch))*576 + c];
    s_ld[c] = s * (1.f/1024.f);
  }
  __syncthreads();
  if (t < 144){
    float a = rb[t];
    for (int c=0;c<576;c++) a = fmaf(rw[(size_t)t*576+c], s_ld[c], a);
    r_ld[t] = fmaxf(a, 0.f);
  }
  __syncthreads();
  for (int d=t; d<576; d+=256){
    float a = eb[d];
    for (int j=0;j<144;j++) a = fmaf(ew[(size_t)d*144+j], r_ld[j], a);
    gate4[b*576+d] = sigmoidf_(a);
  }
}

// ---------------- wavelet reconstruct into A1 pos-major cols 0..192 (lda=320)
__global__ __launch_bounds__(192) void recon(const float* __restrict__ xllout, const float* __restrict__ h2o,
                                             float* __restrict__ A1){
  int bl = blockIdx.x; int b = bl >> 10, lr = bl & 1023;
  int c = threadIdx.x;
  int i = lr >> 5, j = lr & 31;
  float f0 = xllout[(size_t)bl*192 + c];
  const float* hp = &h2o[(size_t)bl*576 + 3*c];
  float f1 = hp[0], f2 = hp[1], f3 = hp[2];
  float v00 = 0.5f*(f0 - f1 - f2 + f3);
  float v01 = 0.5f*(f0 - f1 + f2 - f3);
  float v10 = 0.5f*(f0 + f1 - f2 - f3);
  float v11 = 0.5f*(f0 + f1 + f2 + f3);
  size_t base = ((size_t)b*4096 + (size_t)(2*i)*64 + 2*j)*320 + c;
  A1[base]            = v00;
  A1[base + 320]      = v01;
  A1[base + 64*320]   = v10;
  A1[base + 65*320]   = v11;
}

extern "C" void kernel_launch(void* const* d_in, const int* in_sizes, int n_in,
                              void* d_out, int out_size, void* d_ws, size_t ws_size,
                              hipStream_t stream) {
  const float* x         = (const float*)d_in[0];
  const float* in_proj_w = (const float*)d_in[1];
  const float* conv_w    = (const float*)d_in[2];
  const float* conv_b    = (const float*)d_in[3];
  const float* x_proj_w  = (const float*)d_in[4];
  const float* dt_proj_w = (const float*)d_in[5];
  const float* dt_proj_b = (const float*)d_in[6];
  const float* A_logs    = (const float*)d_in[7];
  const float* Dsp       = (const float*)d_in[8];
  const float* out_norm_g= (const float*)d_in[9];
  const float* out_norm_b= (const float*)d_in[10];
  const float* out_proj_w= (const float*)d_in[11];
  const float* norm_g    = (const float*)d_in[12];
  const float* norm_b    = (const float*)d_in[13];
  const float* lp_dw1_w  = (const float*)d_in[14];
  const float* lp_bn1    = (const float*)d_in[15];
  const float* lp_dw2_w  = (const float*)d_in[16];
  const float* lp_bn2    = (const float*)d_in[17];
  const float* se_rw     = (const float*)d_in[18];
  const float* se_rb     = (const float*)d_in[19];
  const float* se_ew     = (const float*)d_in[20];
  const float* se_eb     = (const float*)d_in[21];
  const float* lp_pw_w   = (const float*)d_in[22];
  const float* lp_bn3    = (const float*)d_in[23];
  const float* proj_w    = (const float*)d_in[24];
  const float* proj_bn   = (const float*)d_in[25];
  float* out = (float*)d_out;
  float* ws = (float*)d_ws;

  // time-phased workspace plan (floats) — total 21,959,168 floats = 87.8 MB
  float* xhigh = ws;                   // 2359296  : wav_dec -> dwconv_bn1
  float* xz    = xhigh + 2359296;      // 3145728  : in_proj -> merge_ln      (later h2)
  float* xconv = xz + 3145728;         // 1572864  : dwconv_silu -> scan C    (later gated)
  float* xdbl  = xconv + 1572864;      // 720896   : xproj -> scan C
  float* Pa    = xdbl + 720896;        // 6291456  : scanA -> chain(in-place Hinit) -> scanC  (later h1, h2o)
  float* Sa    = Pa + 6291456;         // 6291456  : scanA -> chain -> yscan -> merge_ln; then A1 (16384*320)
  float* xll   = Sa + 6291456;         // 786432   : wav_dec -> ln192         (later xllout)
  float* xln   = xll + 786432;         // 786432   : ln192 -> in_proj         (later partials 73728)
  float* smean = xln + 786432;         // 2304     (unused now)
  float* gate4 = smean + 2304;         // 2304
  float* Hinit = Pa;       // chain overwrites Pa in place with per-chunk init states
  float* yscan = Sa;       // pass C output (Sa dead after chain)
  float* gated = xconv;    // merge_ln output (xconv dead after pass C)
  float* xllout= xll;      // out_proj output (xll dead after ln192)
  float* h1    = Pa;       // dwconv_bn1 output (Pa dead after pass C)
  float* h2    = xz;       // dwconv_bn2 output (xz dead after merge_ln)
  float* h2o   = Pa;       // pw gemm output (h1 dead after dwconv_bn2)
  float* A1    = Sa;       // recon + xid_t output (yscan dead after merge_ln); 5,242,880 floats
  float* partials = xln;   // mean576p partials (xln dead after in_proj); 73728 floats

  wav_dec<<<dim3(128), dim3(256), 0, stream>>>(x, xll, xhigh);
  ln192<<<dim3(4096), dim3(64), 0, stream>>>(xll, norm_g, norm_b, xln);
  gemm_mfma<0><<<dim3(32,12), dim3(256), 0, stream>>>(xln, in_proj_w, xz, 4096, 768, 192, 192,
                                                      nullptr, nullptr, nullptr);
  dwconv_silu<<<dim3(4096), dim3(384), 0, stream>>>(xz, conv_w, conv_b, xconv);
  gemm_xproj<<<dim3(8,1,16), dim3(256), 0, stream>>>(xconv, x_proj_w, xdbl);
  scan_chunks<<<dim3(6,16,16), dim3(256), 0, stream>>>(xconv, xdbl, dt_proj_w, dt_proj_b, A_logs, Pa, Sa);
  scan_chain<<<dim3(6,4,16), dim3(256), 0, stream>>>(Pa, Sa);
  scan_emit<<<dim3(6,16,16), dim3(256), 0, stream>>>(xconv, xdbl, dt_proj_w, dt_proj_b, A_logs, Dsp, Hinit, yscan);
  merge_ln<<<dim3(4096), dim3(64), 0, stream>>>(yscan, xz, out_norm_g, out_norm_b, gated);
  gemm_mfma<0><<<dim3(32,3), dim3(256), 0, stream>>>(gated, out_proj_w, xllout, 4096, 192, 384, 384,
                                                     nullptr, nullptr, nullptr);
  xid_t<<<dim3(256), dim3(256), 0, stream>>>(x, A1);
  dwconv_bn<1><<<dim3(4096), dim3(576), 0, stream>>>(xhigh, lp_dw1_w, lp_bn1, h1);
  dwconv_bn<0><<<dim3(4096), dim3(576), 0, stream>>>(h1, lp_dw2_w, lp_bn2, h2);
  mean576p<<<dim3(9,4,32), dim3(256), 0, stream>>>(h2, partials);
  se_gate<<<dim3(4), dim3(256), 0, stream>>>(partials, se_rw, se_rb, se_ew, se_eb, gate4);
  gemm_mfma<2><<<dim3(32,9), dim3(256), 0, stream>>>(h2, lp_pw_w, h2o, 4096, 576, 576, 576,
                                                     gate4, lp_bn3, nullptr);
  recon<<<dim3(4096), dim3(192), 0, stream>>>(xllout, h2o, A1);
  gemm_mfma<3><<<dim3(128,5), dim3(256), 0, stream>>>(A1, proj_w, out, 16384, 320, 320, 320,
                                                      nullptr, proj_bn, x);
}

// Round 10
// 437.369 us; speedup vs baseline: 1.6326x; 1.1037x over previous
//
#include <hip/hip_runtime.h>
#include <cstdint>

#define EPSF 1e-5f

typedef __attribute__((ext_vector_type(8))) short short8;
typedef __attribute__((ext_vector_type(4))) float f32x4;

__device__ __forceinline__ float sigmoidf_(float x){ return 1.f/(1.f+__expf(-x)); }
__device__ __forceinline__ float siluf_(float x){ return x*sigmoidf_(x); }
// cheap softplus: log1p(e) with e in (0,1] -> __logf(1+e), ~1ulp for arg in [1,2]
__device__ __forceinline__ float softplusf_(float x){
  float e = __expf(-fabsf(x));
  return fmaxf(x,0.f) + __logf(1.f + e);
}
__device__ __forceinline__ int mapdir_(int dir, int l){
  int lt = (dir & 2) ? (1023 - l) : l;
  return (dir & 1) ? (((lt & 31) << 5) | (lt >> 5)) : lt;
}
__device__ __forceinline__ unsigned short f2bf_(float f){
  unsigned int u = __float_as_uint(f);
  u = (u + 0x7FFFu + ((u >> 16) & 1u)) >> 16;
  return (unsigned short)u;
}

// ---------------- wavelet decompose: x[:,0:192] (B,192,64,64) -> xll pos-major (B*1024,192),
// ---------------- xhigh pos-major (B*1024,576) with hc = 3*c + (f-1)
__global__ __launch_bounds__(256) void wav_dec(const float* __restrict__ x,
                                               float* __restrict__ xll, float* __restrict__ xhigh){
  int b = blockIdx.x >> 5, i = blockIdx.x & 31;
  __shared__ float r0[64*65];
  __shared__ float r1[64*65];
  int tid = threadIdx.x;
  for (int c0 = 0; c0 < 192; c0 += 64){
    if (c0) __syncthreads();
    for (int t = tid; t < 1024; t += 256){
      int cc = t >> 4, col4 = (t & 15)*4;
      const float* p0 = &x[(((size_t)b*320 + c0+cc)*64 + 2*i)*64 + col4];
      const float* p1 = &x[(((size_t)b*320 + c0+cc)*64 + 2*i+1)*64 + col4];
      float4 a = *(const float4*)p0;
      float4 bb = *(const float4*)p1;
      r0[cc*65+col4+0]=a.x; r0[cc*65+col4+1]=a.y; r0[cc*65+col4+2]=a.z; r0[cc*65+col4+3]=a.w;
      r1[cc*65+col4+0]=bb.x; r1[cc*65+col4+1]=bb.y; r1[cc*65+col4+2]=bb.z; r1[cc*65+col4+3]=bb.w;
    }
    __syncthreads();
    for (int t = tid; t < 2048; t += 256){
      int cl = t & 63, j = t >> 6;
      float a  = r0[cl*65 + 2*j], bv = r0[cl*65 + 2*j + 1];
      float cv = r1[cl*65 + 2*j], dv = r1[cl*65 + 2*j + 1];
      float f0 = 0.5f*(a+bv+cv+dv);
      float f1 = 0.5f*(a+bv-cv-dv);
      float f2 = 0.5f*(a-bv+cv-dv);
      float f3 = 0.5f*(a-bv-cv+dv);
      int l = i*32 + j; int c = c0 + cl;
      xll[((size_t)b*1024 + l)*192 + c] = f0;
      float* hp = &xhigh[((size_t)b*1024 + l)*576 + 3*c];
      hp[0]=f1; hp[1]=f2; hp[2]=f3;
    }
  }
}

// ---------------- transpose x_id (B,128,64,64) channel-major -> A1 pos-major cols 192..320 (lda=320)
__global__ __launch_bounds__(256) void xid_t(const float* __restrict__ x, float* __restrict__ A1){
  __shared__ float l[128][65];
  int hw0 = (blockIdx.x & 63) * 64;
  int b = blockIdx.x >> 6;
  int tid = threadIdx.x;
  for (int t = tid; t < 2048; t += 256){
    int c2 = t >> 4, h4 = (t & 15) * 4;
    float4 v = *(const float4*)&x[((size_t)(b*320 + 192 + c2))*4096 + hw0 + h4];
    l[c2][h4+0]=v.x; l[c2][h4+1]=v.y; l[c2][h4+2]=v.z; l[c2][h4+3]=v.w;
  }
  __syncthreads();
  for (int t = tid; t < 2048; t += 256){
    int hw = t >> 5, c4 = (t & 31) * 4;
    float4 v = make_float4(l[c4+0][hw], l[c4+1][hw], l[c4+2][hw], l[c4+3][hw]);
    *(float4*)&A1[((size_t)b*4096 + hw0 + hw)*320 + 192 + c4] = v;
  }
}

// ---------------- LN over 192 channels per position
__global__ __launch_bounds__(64) void ln192(const float* __restrict__ xll,
                                            const float* __restrict__ g, const float* __restrict__ bt,
                                            float* __restrict__ xln){
  int p = blockIdx.x; int lane = threadIdx.x;
  const float* row = xll + (size_t)p*192;
  float v0 = row[lane], v1 = row[lane+64], v2 = row[lane+128];
  float s = v0+v1+v2, s2 = v0*v0+v1*v1+v2*v2;
  #pragma unroll
  for (int off=32; off; off>>=1){ s += __shfl_xor(s, off, 64); s2 += __shfl_xor(s2, off, 64); }
  float mean = s*(1.f/192.f);
  float var = s2*(1.f/192.f) - mean*mean;
  float rstd = rsqrtf(var + EPSF);
  float* o = xln + (size_t)p*192;
  o[lane]     = (v0-mean)*rstd*g[lane]     + bt[lane];
  o[lane+64]  = (v1-mean)*rstd*g[lane+64]  + bt[lane+64];
  o[lane+128] = (v2-mean)*rstd*g[lane+128] + bt[lane+128];
}

// ---------------- bf16 MFMA GEMM: C[M,N] = A[M,K] * W[N,K]^T, tile 128x64, 4 waves.
// MODE 0: plain pos-major out. MODE 2: A scaled by gate[b][k], BN epilogue.
// MODE 3: BN + residual epilogue, channel-major out (A must be full pos-major, lda=K).
template<int MODE>
__global__ __launch_bounds__(256) void gemm_mfma(
    const float* __restrict__ A, const float* __restrict__ W, float* __restrict__ C,
    int M, int N, int K, int lda,
    const float* __restrict__ gate, const float* __restrict__ bn, const float* __restrict__ xres)
{
  __shared__ unsigned short As[128][40];   // [m][k], +8 pad: 80B rows, 16B-aligned, ~2-way banks
  __shared__ unsigned short Ws[64][40];
  int tid = threadIdx.x;
  int lane = tid & 63, w = tid >> 6;
  int wy = w >> 1, wx = w & 1;
  int frow = lane & 15, fk = (lane >> 4) * 8;
  int m0 = blockIdx.x * 128, n0 = blockIdx.y * 64;
  f32x4 acc[4][2];
  #pragma unroll
  for (int i=0;i<4;i++)
    #pragma unroll
    for (int j=0;j<2;j++) acc[i][j] = (f32x4){0.f,0.f,0.f,0.f};

  for (int k0 = 0; k0 < K; k0 += 32){
    #pragma unroll
    for (int r=0;r<4;r++){
      int fid = tid + 256*r;
      int m = fid >> 3, k4 = (fid & 7)*4;
      float4 v = *(const float4*)&A[(size_t)(m0+m)*lda + k0 + k4];
      if (MODE==2){
        int b = (m0+m) >> 10;
        v.x *= gate[b*576 + k0+k4+0]; v.y *= gate[b*576 + k0+k4+1];
        v.z *= gate[b*576 + k0+k4+2]; v.w *= gate[b*576 + k0+k4+3];
      }
      As[m][k4+0]=f2bf_(v.x); As[m][k4+1]=f2bf_(v.y);
      As[m][k4+2]=f2bf_(v.z); As[m][k4+3]=f2bf_(v.w);
    }
    #pragma unroll
    for (int r=0;r<2;r++){
      int fid = tid + 256*r;
      int n = fid >> 3, k4 = (fid & 7)*4;
      float4 v = *(const float4*)&W[(size_t)(n0+n)*K + k0 + k4];
      Ws[n][k4+0]=f2bf_(v.x); Ws[n][k4+1]=f2bf_(v.y);
      Ws[n][k4+2]=f2bf_(v.z); Ws[n][k4+3]=f2bf_(v.w);
    }
    __syncthreads();
    short8 af[4], bfr[2];
    #pragma unroll
    for (int mt=0;mt<4;mt++) af[mt] = *(const short8*)&As[wy*64 + mt*16 + frow][fk];
    #pragma unroll
    for (int nt=0;nt<2;nt++) bfr[nt] = *(const short8*)&Ws[wx*32 + nt*16 + frow][fk];
    #pragma unroll
    for (int mt=0;mt<4;mt++)
      #pragma unroll
      for (int nt=0;nt<2;nt++)
        acc[mt][nt] = __builtin_amdgcn_mfma_f32_16x16x32_bf16(af[mt], bfr[nt], acc[mt][nt], 0, 0, 0);
    __syncthreads();
  }

  #pragma unroll
  for (int mt=0;mt<4;mt++){
    int row0 = m0 + wy*64 + mt*16 + (lane>>4)*4;
    #pragma unroll
    for (int nt=0;nt<2;nt++){
      int cg = n0 + wx*32 + nt*16 + frow;
      if (MODE==0){
        #pragma unroll
        for (int i=0;i<4;i++) C[(size_t)(row0+i)*N + cg] = acc[mt][nt][i];
      } else if (MODE==2){
        float sc = bn[cg]*rsqrtf(bn[3*N+cg]+EPSF);
        float sh = bn[N+cg] - bn[2*N+cg]*sc;
        #pragma unroll
        for (int i=0;i<4;i++) C[(size_t)(row0+i)*N + cg] = fmaf(acc[mt][nt][i], sc, sh);
      } else {
        float sc = bn[cg]*rsqrtf(bn[3*N+cg]+EPSF);
        float sh = bn[N+cg] - bn[2*N+cg]*sc;
        int b = row0 >> 12, hw0 = row0 & 4095;
        size_t base = ((size_t)(b*320 + cg))*4096 + hw0;
        float4 xr = *(const float4*)&xres[base];
        float4 ov;
        ov.x = xr.x + fmaf(acc[mt][nt][0], sc, sh);
        ov.y = xr.y + fmaf(acc[mt][nt][1], sc, sh);
        ov.z = xr.z + fmaf(acc[mt][nt][2], sc, sh);
        ov.w = xr.w + fmaf(acc[mt][nt][3], sc, sh);
        *(float4*)&C[base] = ov;
      }
    }
  }
}

// ---------------- depthwise 3x3 + bias + SiLU on xm (first 384 cols of xz rows)
__global__ __launch_bounds__(384) void dwconv_silu(const float* __restrict__ xz,
                                                   const float* __restrict__ cw, const float* __restrict__ cb,
                                                   float* __restrict__ xconv){
  int bl = blockIdx.x; int b = bl >> 10, l = bl & 1023;
  int i = l >> 5, j = l & 31;
  int d = threadIdx.x;
  float w[9];
  #pragma unroll
  for (int t=0;t<9;t++) w[t] = cw[d*9+t];
  float acc = cb[d];
  #pragma unroll
  for (int di=-1;di<=1;di++){
    int ii = i+di; if (ii < 0 || ii > 31) continue;
    #pragma unroll
    for (int dj=-1;dj<=1;dj++){
      int jj = j+dj; if (jj < 0 || jj > 31) continue;
      acc += w[(di+1)*3 + (dj+1)] * xz[((size_t)(b*1024 + ii*32 + jj))*768 + d];
    }
  }
  xconv[(size_t)bl*384 + d] = siluf_(acc);
}

// ---------------- x_proj: per (b,dir) GEMM: xdbl[bk][c<44][l] = sum_d xconv[b, map(l), d] * xpw[dir][c][d]
__global__ __launch_bounds__(256) void gemm_xproj(const float* __restrict__ xconv,
                                                  const float* __restrict__ xpw, float* __restrict__ xdbl){
  __shared__ float As[32][128];
  __shared__ float Ws[32][64];
  int tid = threadIdx.x;
  int tx = tid & 15, ty = tid >> 4;
  int m0 = blockIdx.x * 128;
  int bk = blockIdx.z; int b = bk >> 2, dir = bk & 3;
  const float* Wk = xpw + (size_t)dir*44*384;
  float acc[8][4];
  #pragma unroll
  for (int i=0;i<8;i++)
    #pragma unroll
    for (int j=0;j<4;j++) acc[i][j]=0.f;
  for (int k0=0;k0<384;k0+=32){
    #pragma unroll
    for (int r=0;r<4;r++){
      int fid = tid + 256*r;
      int m = fid >> 3, k4 = (fid & 7)*4;
      int l = m0 + m;
      int row = b*1024 + mapdir_(dir, l);
      float4 v = *(const float4*)&xconv[(size_t)row*384 + k0 + k4];
      As[k4+0][m]=v.x; As[k4+1][m]=v.y; As[k4+2][m]=v.z; As[k4+3][m]=v.w;
    }
    #pragma unroll
    for (int r=0;r<2;r++){
      int fid = tid + 256*r;
      int n = fid >> 3, k4 = (fid & 7)*4;
      float4 v = (n < 44) ? *(const float4*)&Wk[(size_t)n*384 + k0 + k4] : make_float4(0.f,0.f,0.f,0.f);
      Ws[k4+0][n]=v.x; Ws[k4+1][n]=v.y; Ws[k4+2][n]=v.z; Ws[k4+3][n]=v.w;
    }
    __syncthreads();
    #pragma unroll
    for (int kk=0;kk<32;kk++){
      float4 a0 = *(float4*)&As[kk][ty*8];
      float4 a1 = *(float4*)&As[kk][ty*8+4];
      float4 bf = *(float4*)&Ws[kk][tx*4];
      float av[8] = {a0.x,a0.y,a0.z,a0.w,a1.x,a1.y,a1.z,a1.w};
      float bv[4] = {bf.x,bf.y,bf.z,bf.w};
      #pragma unroll
      for (int i=0;i<8;i++)
        #pragma unroll
        for (int j=0;j<4;j++)
          acc[i][j] = fmaf(av[i], bv[j], acc[i][j]);
    }
    __syncthreads();
  }
  float* Cb = xdbl + (size_t)bk*44*1024;
  #pragma unroll
  for (int j=0;j<4;j++){
    int c = tx*4 + j;
    if (c < 44){
      float4 o0 = make_float4(acc[0][j],acc[1][j],acc[2][j],acc[3][j]);
      float4 o1 = make_float4(acc[4][j],acc[5][j],acc[6][j],acc[7][j]);
      *(float4*)&Cb[(size_t)c*1024 + m0 + ty*8]     = o0;
      *(float4*)&Cb[(size_t)c*1024 + m0 + ty*8 + 4] = o1;
    }
  }
}

// ---------------- selective scan pass A: chunk summaries, CL=16, 64 chunks.
// P[n] = exp(Ar[n]*sum(delta)) exactly (product of exps). h-loop uses guarded fast-exp chain.
__global__ __launch_bounds__(256, 4) void scan_chunks(const float* __restrict__ xconv, const float* __restrict__ xdbl,
    const float* __restrict__ dtw_all, const float* __restrict__ dtb_all, const float* __restrict__ alog_all,
    float* __restrict__ Pa, float* __restrict__ Sa){
  __shared__ float xs[28][64];
  int tid = threadIdx.x;
  int dl = tid & 63, cs = tid >> 6;
  int d = blockIdx.x*64 + dl;
  int chunk = blockIdx.y*4 + cs;
  int bk = blockIdx.z; int b = bk >> 2, k = bk & 3;
  const float* xd = xdbl + (size_t)bk*44*1024;
  int L0 = blockIdx.y*64;
  for (int t = tid; t < 28*16; t += 256){
    int c = t >> 4, col = (t & 15) << 2;
    float4 v = *(const float4*)&xd[(size_t)c*1024 + L0 + col];
    *(float4*)&xs[c][col] = v;
  }
  float dtw[12];
  #pragma unroll
  for (int r=0;r<12;r++) dtw[r] = dtw_all[(size_t)(k*384 + d)*12 + r];
  float dtb = dtb_all[k*384 + d];
  float Ar[16];
  #pragma unroll
  for (int n=0;n<16;n++) Ar[n] = -__expf(alog_all[(size_t)(k*384 + d)*16 + n]);
  bool linear = true;
  #pragma unroll
  for (int n=0;n<16;n++) linear = linear && (fabsf(Ar[n] + (float)(n+1)) <= 1e-3f*(float)(n+1));
  float h[16];
  #pragma unroll
  for (int n=0;n<16;n++) h[n]=0.f;
  float sdelta = 0.f;
  __syncthreads();
  int l0 = chunk*16, c0 = cs*16;
  if (linear){
    for (int li=0; li<16; li++){
      int l = l0 + li, col = c0 + li;
      float u = xconv[((size_t)(b*1024 + mapdir_(k, l)))*384 + d];
      float dr = dtb;
      #pragma unroll
      for (int r=0;r<12;r++) dr = fmaf(dtw[r], xs[r][col], dr);
      float delta = softplusf_(dr);
      float du = delta * u;
      sdelta += delta;
      float q = __expf(-delta), e = 1.f;
      #pragma unroll
      for (int n=0;n<16;n++){
        e *= q;
        h[n] = fmaf(e, h[n], du * xs[12+n][col]);
      }
    }
  } else {
    for (int li=0; li<16; li++){
      int l = l0 + li, col = c0 + li;
      float u = xconv[((size_t)(b*1024 + mapdir_(k, l)))*384 + d];
      float dr = dtb;
      #pragma unroll
      for (int r=0;r<12;r++) dr = fmaf(dtw[r], xs[r][col], dr);
      float delta = softplusf_(dr);
      float du = delta * u;
      sdelta += delta;
      #pragma unroll
      for (int n=0;n<16;n++){
        float e = __expf(delta * Ar[n]);
        h[n] = fmaf(e, h[n], du * xs[12+n][col]);
      }
    }
  }
  size_t base = (((size_t)bk*64 + chunk)*16)*384 + d;
  #pragma unroll
  for (int n=0;n<16;n++){
    Pa[base + (size_t)n*384] = __expf(sdelta * Ar[n]);
    Sa[base + (size_t)n*384] = h[n];
  }
}

// ---------------- pass B: serial chain over 64 chunk states; writes Hinit IN-PLACE into Pa.
__global__ __launch_bounds__(256) void scan_chain(float* __restrict__ Pa, const float* __restrict__ Sa){
  int dl = threadIdx.x & 63, nl = threadIdx.x >> 6;
  int d = blockIdx.x*64 + dl;
  int n = blockIdx.y*4 + nl;
  int bk = blockIdx.z;
  float h = 0.f;
  for (int c=0;c<64;c++){
    size_t idx = (((size_t)bk*64 + c)*16 + n)*384 + d;
    float p = Pa[idx], s = Sa[idx];
    Pa[idx] = h;
    h = fmaf(p, h, s);
  }
}

// ---------------- pass C: re-scan with Hinit (in Pa), emit y. LDS-stages all 44 xdbl rows.
__global__ __launch_bounds__(256, 4) void scan_emit(const float* __restrict__ xconv, const float* __restrict__ xdbl,
    const float* __restrict__ dtw_all, const float* __restrict__ dtb_all, const float* __restrict__ alog_all,
    const float* __restrict__ Ds, const float* __restrict__ Hinit, float* __restrict__ yout){
  __shared__ float xs[44][64];
  int tid = threadIdx.x;
  int dl = tid & 63, cs = tid >> 6;
  int d = blockIdx.x*64 + dl;
  int chunk = blockIdx.y*4 + cs;
  int bk = blockIdx.z; int b = bk >> 2, k = bk & 3;
  const float* xd = xdbl + (size_t)bk*44*1024;
  int L0 = blockIdx.y*64;
  for (int t = tid; t < 44*16; t += 256){
    int c = t >> 4, col = (t & 15) << 2;
    float4 v = *(const float4*)&xd[(size_t)c*1024 + L0 + col];
    *(float4*)&xs[c][col] = v;
  }
  float dtw[12];
  #pragma unroll
  for (int r=0;r<12;r++) dtw[r] = dtw_all[(size_t)(k*384 + d)*12 + r];
  float dtb = dtb_all[k*384 + d];
  float Dv = Ds[k*384 + d];
  float Ar[16];
  #pragma unroll
  for (int n=0;n<16;n++) Ar[n] = -__expf(alog_all[(size_t)(k*384 + d)*16 + n]);
  bool linear = true;
  #pragma unroll
  for (int n=0;n<16;n++) linear = linear && (fabsf(Ar[n] + (float)(n+1)) <= 1e-3f*(float)(n+1));
  float h[16];
  size_t hbase = (((size_t)bk*64 + chunk)*16)*384 + d;
  #pragma unroll
  for (int n=0;n<16;n++) h[n] = Hinit[hbase + (size_t)n*384];
  __syncthreads();
  int l0 = chunk*16, c0 = cs*16;
  if (linear){
    for (int li=0; li<16; li++){
      int l = l0 + li, col = c0 + li;
      float u = xconv[((size_t)(b*1024 + mapdir_(k, l)))*384 + d];
      float dr = dtb;
      #pragma unroll
      for (int r=0;r<12;r++) dr = fmaf(dtw[r], xs[r][col], dr);
      float delta = softplusf_(dr);
      float du = delta * u;
      float y = Dv * u;
      float q = __expf(-delta), e = 1.f;
      #pragma unroll
      for (int n=0;n<16;n++){
        e *= q;
        h[n] = fmaf(e, h[n], du * xs[12+n][col]);
        y = fmaf(h[n], xs[28+n][col], y);
      }
      yout[((size_t)bk*1024 + l)*384 + d] = y;
    }
  } else {
    for (int li=0; li<16; li++){
      int l = l0 + li, col = c0 + li;
      float u = xconv[((size_t)(b*1024 + mapdir_(k, l)))*384 + d];
      float dr = dtb;
      #pragma unroll
      for (int r=0;r<12;r++) dr = fmaf(dtw[r], xs[r][col], dr);
      float delta = softplusf_(dr);
      float du = delta * u;
      float y = Dv * u;
      #pragma unroll
      for (int n=0;n<16;n++){
        float e = __expf(delta * Ar[n]);
        h[n] = fmaf(e, h[n], du * xs[12+n][col]);
        y = fmaf(h[n], xs[28+n][col], y);
      }
      yout[((size_t)bk*1024 + l)*384 + d] = y;
    }
  }
}

// ---------------- merge 4 directions + LN(384) + *silu(z) -> gated pos-major
__global__ __launch_bounds__(64) void merge_ln(const float* __restrict__ ysc, const float* __restrict__ xz,
    const float* __restrict__ ong, const float* __restrict__ onb, float* __restrict__ gated){
  int bl = blockIdx.x; int b = bl >> 10, l = bl & 1023;
  int lane = threadIdx.x;
  int p1 = ((l & 31) << 5) | (l >> 5);
  const float* y0 = ysc + ((size_t)(b*4+0)*1024 + l)*384;
  const float* y1 = ysc + ((size_t)(b*4+1)*1024 + p1)*384;
  const float* y2 = ysc + ((size_t)(b*4+2)*1024 + (1023-l))*384;
  const float* y3 = ysc + ((size_t)(b*4+3)*1024 + (1023-p1))*384;
  float v[6]; float s = 0.f, s2 = 0.f;
  #pragma unroll
  for (int r=0;r<6;r++){
    int d = lane + 64*r;
    float t = y0[d] + y1[d] + y2[d] + y3[d];
    v[r] = t; s += t; s2 += t*t;
  }
  #pragma unroll
  for (int off=32; off; off>>=1){ s += __shfl_xor(s, off, 64); s2 += __shfl_xor(s2, off, 64); }
  float mean = s*(1.f/384.f);
  float var = s2*(1.f/384.f) - mean*mean;
  float rstd = rsqrtf(var + EPSF);
  const float* zrow = xz + (size_t)bl*768 + 384;
  float* grow = gated + (size_t)bl*384;
  #pragma unroll
  for (int r=0;r<6;r++){
    int d = lane + 64*r;
    float z = zrow[d];
    grow[d] = ((v[r]-mean)*rstd*ong[d] + onb[d]) * siluf_(z);
  }
}

// ---------------- high path depthwise 3x3 + BN (+ReLU)
template<int RELU>
__global__ __launch_bounds__(576) void dwconv_bn(const float* __restrict__ hin,
    const float* __restrict__ dw, const float* __restrict__ bn, float* __restrict__ hout){
  int bl = blockIdx.x; int b = bl >> 10, l = bl & 1023;
  int i = l >> 5, j = l & 31;
  int d = threadIdx.x;
  float w[9];
  #pragma unroll
  for (int t=0;t<9;t++) w[t] = dw[d*9+t];
  float acc = 0.f;
  #pragma unroll
  for (int di=-1;di<=1;di++){
    int ii = i+di; if (ii < 0 || ii > 31) continue;
    #pragma unroll
    for (int dj=-1;dj<=1;dj++){
      int jj = j+dj; if (jj < 0 || jj > 31) continue;
      acc += w[(di+1)*3 + (dj+1)] * hin[((size_t)(b*1024 + ii*32 + jj))*576 + d];
    }
  }
  float sc = bn[d] * rsqrtf(bn[3*576+d] + EPSF);
  float vv = (acc - bn[2*576+d])*sc + bn[576+d];
  if (RELU) vv = fmaxf(vv, 0.f);
  hout[(size_t)bl*576 + d] = vv;
}

// ---------------- spatial partial sums of h2: grid (9, 4, 32), each block sums 32 positions
__global__ __launch_bounds__(256) void mean576p(const float* __restrict__ h2, float* __restrict__ partials){
  __shared__ float red[256];
  int dg = blockIdx.x, b = blockIdx.y, ch = blockIdx.z;
  int dl = threadIdx.x & 63, lq = threadIdx.x >> 6;
  int d = dg*64 + dl;
  int l0 = ch*32;
  float ps = 0.f;
  #pragma unroll
  for (int li = 0; li < 8; li++){
    int l = l0 + lq + li*4;
    ps += h2[((size_t)(b*1024 + l))*576 + d];
  }
  red[threadIdx.x] = ps;
  __syncthreads();
  if (threadIdx.x < 64){
    float ssum = red[threadIdx.x] + red[threadIdx.x+64] + red[threadIdx.x+128] + red[threadIdx.x+192];
    partials[((size_t)(b*32 + ch))*576 + dg*64 + threadIdx.x] = ssum;
  }
}

// ---------------- SE gate (sums 32 partials per channel, then two tiny GEMVs)
__global__ __launch_bounds__(256) void se_gate(const float* __restrict__ partials,
    const float* __restrict__ rw, const float* __restrict__ rb,
    const float* __restrict__ ew, const float* __restrict__ eb, float* __restrict__ gate4){
  __shared__ float s_ld[576];
  __shared__ float r_ld[144];
  int b = blockIdx.x, t = threadIdx.x;
  for (int c=t; c<576; c+=256){
    float s = 0.f;
    #pragma unroll
    for (int ch=0; ch<32; ch++) s += partials[((size_t)(b*32 + ch))*576 + c];
    s_ld[c] = s * (1.f/1024.f);
  }
  __syncthreads();
  if (t < 144){
    float a = rb[t];
    for (int c=0;c<576;c++) a = fmaf(rw[(size_t)t*576+c], s_ld[c], a);
    r_ld[t] = fmaxf(a, 0.f);
  }
  __syncthreads();
  for (int d=t; d<576; d+=256){
    float a = eb[d];
    for (int j=0;j<144;j++) a = fmaf(ew[(size_t)d*144+j], r_ld[j], a);
    gate4[b*576+d] = sigmoidf_(a);
  }
}

// ---------------- wavelet reconstruct into A1 pos-major cols 0..192 (lda=320)
__global__ __launch_bounds__(192) void recon(const float* __restrict__ xllout, const float* __restrict__ h2o,
                                             float* __restrict__ A1){
  int bl = blockIdx.x; int b = bl >> 10, lr = bl & 1023;
  int c = threadIdx.x;
  int i = lr >> 5, j = lr & 31;
  float f0 = xllout[(size_t)bl*192 + c];
  const float* hp = &h2o[(size_t)bl*576 + 3*c];
  float f1 = hp[0], f2 = hp[1], f3 = hp[2];
  float v00 = 0.5f*(f0 - f1 - f2 + f3);
  float v01 = 0.5f*(f0 - f1 + f2 - f3);
  float v10 = 0.5f*(f0 + f1 - f2 - f3);
  float v11 = 0.5f*(f0 + f1 + f2 + f3);
  size_t base = ((size_t)b*4096 + (size_t)(2*i)*64 + 2*j)*320 + c;
  A1[base]            = v00;
  A1[base + 320]      = v01;
  A1[base + 64*320]   = v10;
  A1[base + 65*320]   = v11;
}

extern "C" void kernel_launch(void* const* d_in, const int* in_sizes, int n_in,
                              void* d_out, int out_size, void* d_ws, size_t ws_size,
                              hipStream_t stream) {
  const float* x         = (const float*)d_in[0];
  const float* in_proj_w = (const float*)d_in[1];
  const float* conv_w    = (const float*)d_in[2];
  const float* conv_b    = (const float*)d_in[3];
  const float* x_proj_w  = (const float*)d_in[4];
  const float* dt_proj_w = (const float*)d_in[5];
  const float* dt_proj_b = (const float*)d_in[6];
  const float* A_logs    = (const float*)d_in[7];
  const float* Dsp       = (const float*)d_in[8];
  const float* out_norm_g= (const float*)d_in[9];
  const float* out_norm_b= (const float*)d_in[10];
  const float* out_proj_w= (const float*)d_in[11];
  const float* norm_g    = (const float*)d_in[12];
  const float* norm_b    = (const float*)d_in[13];
  const float* lp_dw1_w  = (const float*)d_in[14];
  const float* lp_bn1    = (const float*)d_in[15];
  const float* lp_dw2_w  = (const float*)d_in[16];
  const float* lp_bn2    = (const float*)d_in[17];
  const float* se_rw     = (const float*)d_in[18];
  const float* se_rb     = (const float*)d_in[19];
  const float* se_ew     = (const float*)d_in[20];
  const float* se_eb     = (const float*)d_in[21];
  const float* lp_pw_w   = (const float*)d_in[22];
  const float* lp_bn3    = (const float*)d_in[23];
  const float* proj_w    = (const float*)d_in[24];
  const float* proj_bn   = (const float*)d_in[25];
  float* out = (float*)d_out;
  float* ws = (float*)d_ws;

  // time-phased workspace plan (floats) — total 21,959,168 floats = 87.8 MB
  float* xhigh = ws;                   // 2359296  : wav_dec -> dwconv_bn1
  float* xz    = xhigh + 2359296;      // 3145728  : in_proj -> merge_ln      (later h2)
  float* xconv = xz + 3145728;         // 1572864  : dwconv_silu -> scan C    (later gated)
  float* xdbl  = xconv + 1572864;      // 720896   : xproj -> scan C
  float* Pa    = xdbl + 720896;        // 6291456  : scanA -> chain(in-place Hinit) -> scanC  (later h1, h2o)
  float* Sa    = Pa + 6291456;         // 6291456  : scanA -> chain -> yscan -> merge_ln; then A1 (16384*320)
  float* xll   = Sa + 6291456;         // 786432   : wav_dec -> ln192         (later xllout)
  float* xln   = xll + 786432;         // 786432   : ln192 -> in_proj         (later partials 73728)
  float* smean = xln + 786432;         // 2304     (unused now)
  float* gate4 = smean + 2304;         // 2304
  float* Hinit = Pa;       // chain overwrites Pa in place with per-chunk init states
  float* yscan = Sa;       // pass C output (Sa dead after chain)
  float* gated = xconv;    // merge_ln output (xconv dead after pass C)
  float* xllout= xll;      // out_proj output (xll dead after ln192)
  float* h1    = Pa;       // dwconv_bn1 output (Pa dead after pass C)
  float* h2    = xz;       // dwconv_bn2 output (xz dead after merge_ln)
  float* h2o   = Pa;       // pw gemm output (h1 dead after dwconv_bn2)
  float* A1    = Sa;       // recon + xid_t output (yscan dead after merge_ln); 5,242,880 floats
  float* partials = xln;   // mean576p partials (xln dead after in_proj); 73728 floats

  wav_dec<<<dim3(128), dim3(256), 0, stream>>>(x, xll, xhigh);
  ln192<<<dim3(4096), dim3(64), 0, stream>>>(xll, norm_g, norm_b, xln);
  gemm_mfma<0><<<dim3(32,12), dim3(256), 0, stream>>>(xln, in_proj_w, xz, 4096, 768, 192, 192,
                                                      nullptr, nullptr, nullptr);
  dwconv_silu<<<dim3(4096), dim3(384), 0, stream>>>(xz, conv_w, conv_b, xconv);
  gemm_xproj<<<dim3(8,1,16), dim3(256), 0, stream>>>(xconv, x_proj_w, xdbl);
  scan_chunks<<<dim3(6,16,16), dim3(256), 0, stream>>>(xconv, xdbl, dt_proj_w, dt_proj_b, A_logs, Pa, Sa);
  scan_chain<<<dim3(6,4,16), dim3(256), 0, stream>>>(Pa, Sa);
  scan_emit<<<dim3(6,16,16), dim3(256), 0, stream>>>(xconv, xdbl, dt_proj_w, dt_proj_b, A_logs, Dsp, Hinit, yscan);
  merge_ln<<<dim3(4096), dim3(64), 0, stream>>>(yscan, xz, out_norm_g, out_norm_b, gated);
  gemm_mfma<0><<<dim3(32,3), dim3(256), 0, stream>>>(gated, out_proj_w, xllout, 4096, 192, 384, 384,
                                                     nullptr, nullptr, nullptr);
  xid_t<<<dim3(256), dim3(256), 0, stream>>>(x, A1);
  dwconv_bn<1><<<dim3(4096), dim3(576), 0, stream>>>(xhigh, lp_dw1_w, lp_bn1, h1);
  dwconv_bn<0><<<dim3(4096), dim3(576), 0, stream>>>(h1, lp_dw2_w, lp_bn2, h2);
  mean576p<<<dim3(9,4,32), dim3(256), 0, stream>>>(h2, partials);
  se_gate<<<dim3(4), dim3(256), 0, stream>>>(partials, se_rw, se_rb, se_ew, se_eb, gate4);
  gemm_mfma<2><<<dim3(32,9), dim3(256), 0, stream>>>(h2, lp_pw_w, h2o, 4096, 576, 576, 576,
                                                     gate4, lp_bn3, nullptr);
  recon<<<dim3(4096), dim3(192), 0, stream>>>(xllout, h2o, A1);
  gemm_mfma<3><<<dim3(128,5), dim3(256), 0, stream>>>(A1, proj_w, out, 16384, 320, 320, 320,
                                                      nullptr, proj_bn, x);
}

// Round 14
// 379.727 us; speedup vs baseline: 1.8805x; 1.1518x over previous
//
#include <hip/hip_runtime.h>
#include <cstdint>

#define EPSF 1e-5f

typedef __attribute__((ext_vector_type(8))) short short8;
typedef __attribute__((ext_vector_type(4))) float f32x4;

__device__ __forceinline__ float sigmoidf_(float x){ return 1.f/(1.f+__expf(-x)); }
__device__ __forceinline__ float siluf_(float x){ return x*sigmoidf_(x); }
// cheap softplus: log1p(e) with e in (0,1] -> __logf(1+e), ~1ulp for arg in [1,2]
__device__ __forceinline__ float softplusf_(float x){
  float e = __expf(-fabsf(x));
  return fmaxf(x,0.f) + __logf(1.f + e);
}
__device__ __forceinline__ int mapdir_(int dir, int l){
  int lt = (dir & 2) ? (1023 - l) : l;
  return (dir & 1) ? (((lt & 31) << 5) | (lt >> 5)) : lt;
}
__device__ __forceinline__ unsigned short f2bf_(float f){
  unsigned int u = __float_as_uint(f);
  u = (u + 0x7FFFu + ((u >> 16) & 1u)) >> 16;
  return (unsigned short)u;
}

// ---------------- wavelet decompose: x[:,0:192] (B,192,64,64) -> xll pos-major (B*1024,192),
// ---------------- xhigh pos-major (B*1024,576) with hc = 3*c + (f-1)
__global__ __launch_bounds__(256) void wav_dec(const float* __restrict__ x,
                                               float* __restrict__ xll, float* __restrict__ xhigh){
  int b = blockIdx.x >> 5, i = blockIdx.x & 31;
  __shared__ float r0[64*65];
  __shared__ float r1[64*65];
  int tid = threadIdx.x;
  for (int c0 = 0; c0 < 192; c0 += 64){
    if (c0) __syncthreads();
    for (int t = tid; t < 1024; t += 256){
      int cc = t >> 4, col4 = (t & 15)*4;
      const float* p0 = &x[(((size_t)b*320 + c0+cc)*64 + 2*i)*64 + col4];
      const float* p1 = &x[(((size_t)b*320 + c0+cc)*64 + 2*i+1)*64 + col4];
      float4 a = *(const float4*)p0;
      float4 bb = *(const float4*)p1;
      r0[cc*65+col4+0]=a.x; r0[cc*65+col4+1]=a.y; r0[cc*65+col4+2]=a.z; r0[cc*65+col4+3]=a.w;
      r1[cc*65+col4+0]=bb.x; r1[cc*65+col4+1]=bb.y; r1[cc*65+col4+2]=bb.z; r1[cc*65+col4+3]=bb.w;
    }
    __syncthreads();
    for (int t = tid; t < 2048; t += 256){
      int cl = t & 63, j = t >> 6;
      float a  = r0[cl*65 + 2*j], bv = r0[cl*65 + 2*j + 1];
      float cv = r1[cl*65 + 2*j], dv = r1[cl*65 + 2*j + 1];
      float f0 = 0.5f*(a+bv+cv+dv);
      float f1 = 0.5f*(a+bv-cv-dv);
      float f2 = 0.5f*(a-bv+cv-dv);
      float f3 = 0.5f*(a-bv-cv+dv);
      int l = i*32 + j; int c = c0 + cl;
      xll[((size_t)b*1024 + l)*192 + c] = f0;
      float* hp = &xhigh[((size_t)b*1024 + l)*576 + 3*c];
      hp[0]=f1; hp[1]=f2; hp[2]=f3;
    }
  }
}

// ---------------- transpose x_id (B,128,64,64) channel-major -> A1 pos-major cols 192..320 (lda=320)
__global__ __launch_bounds__(256) void xid_t(const float* __restrict__ x, float* __restrict__ A1){
  __shared__ float l[128][65];
  int hw0 = (blockIdx.x & 63) * 64;
  int b = blockIdx.x >> 6;
  int tid = threadIdx.x;
  for (int t = tid; t < 2048; t += 256){
    int c2 = t >> 4, h4 = (t & 15) * 4;
    float4 v = *(const float4*)&x[((size_t)(b*320 + 192 + c2))*4096 + hw0 + h4];
    l[c2][h4+0]=v.x; l[c2][h4+1]=v.y; l[c2][h4+2]=v.z; l[c2][h4+3]=v.w;
  }
  __syncthreads();
  for (int t = tid; t < 2048; t += 256){
    int hw = t >> 5, c4 = (t & 31) * 4;
    float4 v = make_float4(l[c4+0][hw], l[c4+1][hw], l[c4+2][hw], l[c4+3][hw]);
    *(float4*)&A1[((size_t)b*4096 + hw0 + hw)*320 + 192 + c4] = v;
  }
}

// ---------------- LN over 192 channels per position
__global__ __launch_bounds__(64) void ln192(const float* __restrict__ xll,
                                            const float* __restrict__ g, const float* __restrict__ bt,
                                            float* __restrict__ xln){
  int p = blockIdx.x; int lane = threadIdx.x;
  const float* row = xll + (size_t)p*192;
  float v0 = row[lane], v1 = row[lane+64], v2 = row[lane+128];
  float s = v0+v1+v2, s2 = v0*v0+v1*v1+v2*v2;
  #pragma unroll
  for (int off=32; off; off>>=1){ s += __shfl_xor(s, off, 64); s2 += __shfl_xor(s2, off, 64); }
  float mean = s*(1.f/192.f);
  float var = s2*(1.f/192.f) - mean*mean;
  float rstd = rsqrtf(var + EPSF);
  float* o = xln + (size_t)p*192;
  o[lane]     = (v0-mean)*rstd*g[lane]     + bt[lane];
  o[lane+64]  = (v1-mean)*rstd*g[lane+64]  + bt[lane+64];
  o[lane+128] = (v2-mean)*rstd*g[lane+128] + bt[lane+128];
}

// ---------------- bf16 MFMA GEMM: C[M,N] = A[M,K] * W[N,K]^T, tile 64x64, 4 waves (2x2),
// each wave 32x32 = 2x2 16x16 frags. Smaller tile -> 2x block count -> latency hiding via TLP.
// MODE 0: plain pos-major out. MODE 2: A scaled by gate[b][k], BN epilogue.
// MODE 3: BN + residual epilogue, channel-major out (A must be full pos-major, lda=K).
template<int MODE>
__global__ __launch_bounds__(256) void gemm_mfma(
    const float* __restrict__ A, const float* __restrict__ W, float* __restrict__ C,
    int M, int N, int K, int lda,
    const float* __restrict__ gate, const float* __restrict__ bn, const float* __restrict__ xres)
{
  __shared__ unsigned short As[64][40];   // [m][k], +8 pad: 80B rows, 16B-aligned
  __shared__ unsigned short Ws[64][40];
  int tid = threadIdx.x;
  int lane = tid & 63, w = tid >> 6;
  int wy = w >> 1, wx = w & 1;
  int frow = lane & 15, fk = (lane >> 4) * 8;
  int m0 = blockIdx.x * 64, n0 = blockIdx.y * 64;
  f32x4 acc[2][2];
  #pragma unroll
  for (int i=0;i<2;i++)
    #pragma unroll
    for (int j=0;j<2;j++) acc[i][j] = (f32x4){0.f,0.f,0.f,0.f};

  for (int k0 = 0; k0 < K; k0 += 32){
    #pragma unroll
    for (int r=0;r<2;r++){
      int fid = tid + 256*r;
      int m = fid >> 3, k4 = (fid & 7)*4;
      float4 v = *(const float4*)&A[(size_t)(m0+m)*lda + k0 + k4];
      if (MODE==2){
        int b = (m0+m) >> 10;
        v.x *= gate[b*576 + k0+k4+0]; v.y *= gate[b*576 + k0+k4+1];
        v.z *= gate[b*576 + k0+k4+2]; v.w *= gate[b*576 + k0+k4+3];
      }
      As[m][k4+0]=f2bf_(v.x); As[m][k4+1]=f2bf_(v.y);
      As[m][k4+2]=f2bf_(v.z); As[m][k4+3]=f2bf_(v.w);
    }
    #pragma unroll
    for (int r=0;r<2;r++){
      int fid = tid + 256*r;
      int n = fid >> 3, k4 = (fid & 7)*4;
      float4 v = *(const float4*)&W[(size_t)(n0+n)*K + k0 + k4];
      Ws[n][k4+0]=f2bf_(v.x); Ws[n][k4+1]=f2bf_(v.y);
      Ws[n][k4+2]=f2bf_(v.z); Ws[n][k4+3]=f2bf_(v.w);
    }
    __syncthreads();
    short8 af[2], bfr[2];
    #pragma unroll
    for (int mt=0;mt<2;mt++) af[mt] = *(const short8*)&As[wy*32 + mt*16 + frow][fk];
    #pragma unroll
    for (int nt=0;nt<2;nt++) bfr[nt] = *(const short8*)&Ws[wx*32 + nt*16 + frow][fk];
    #pragma unroll
    for (int mt=0;mt<2;mt++)
      #pragma unroll
      for (int nt=0;nt<2;nt++)
        acc[mt][nt] = __builtin_amdgcn_mfma_f32_16x16x32_bf16(af[mt], bfr[nt], acc[mt][nt], 0, 0, 0);
    __syncthreads();
  }

  #pragma unroll
  for (int mt=0;mt<2;mt++){
    int row0 = m0 + wy*32 + mt*16 + (lane>>4)*4;
    #pragma unroll
    for (int nt=0;nt<2;nt++){
      int cg = n0 + wx*32 + nt*16 + frow;
      if (MODE==0){
        #pragma unroll
        for (int i=0;i<4;i++) C[(size_t)(row0+i)*N + cg] = acc[mt][nt][i];
      } else if (MODE==2){
        float sc = bn[cg]*rsqrtf(bn[3*N+cg]+EPSF);
        float sh = bn[N+cg] - bn[2*N+cg]*sc;
        #pragma unroll
        for (int i=0;i<4;i++) C[(size_t)(row0+i)*N + cg] = fmaf(acc[mt][nt][i], sc, sh);
      } else {
        float sc = bn[cg]*rsqrtf(bn[3*N+cg]+EPSF);
        float sh = bn[N+cg] - bn[2*N+cg]*sc;
        int b = row0 >> 12, hw0 = row0 & 4095;
        size_t base = ((size_t)(b*320 + cg))*4096 + hw0;
        float4 xr = *(const float4*)&xres[base];
        float4 ov;
        ov.x = xr.x + fmaf(acc[mt][nt][0], sc, sh);
        ov.y = xr.y + fmaf(acc[mt][nt][1], sc, sh);
        ov.z = xr.z + fmaf(acc[mt][nt][2], sc, sh);
        ov.w = xr.w + fmaf(acc[mt][nt][3], sc, sh);
        *(float4*)&C[base] = ov;
      }
    }
  }
}

// ---------------- depthwise 3x3 + bias + SiLU on xm (first 384 cols of xz rows)
__global__ __launch_bounds__(384) void dwconv_silu(const float* __restrict__ xz,
                                                   const float* __restrict__ cw, const float* __restrict__ cb,
                                                   float* __restrict__ xconv){
  int bl = blockIdx.x; int b = bl >> 10, l = bl & 1023;
  int i = l >> 5, j = l & 31;
  int d = threadIdx.x;
  float w[9];
  #pragma unroll
  for (int t=0;t<9;t++) w[t] = cw[d*9+t];
  float acc = cb[d];
  #pragma unroll
  for (int di=-1;di<=1;di++){
    int ii = i+di; if (ii < 0 || ii > 31) continue;
    #pragma unroll
    for (int dj=-1;dj<=1;dj++){
      int jj = j+dj; if (jj < 0 || jj > 31) continue;
      acc += w[(di+1)*3 + (dj+1)] * xz[((size_t)(b*1024 + ii*32 + jj))*768 + d];
    }
  }
  xconv[(size_t)bl*384 + d] = siluf_(acc);
}

// ---------------- x_proj via bf16 MFMA: per (b,dir): xdbl[bk][c<44][l] = sum_d xconv[b,map(l),d]*xpw[dir][c][d]
// 64x64 tile (N padded 44->64, zero W rows), grid (16,1,16)=256 blocks; LDS-transpose epilogue.
__global__ __launch_bounds__(256) void gemm_xproj_mfma(const float* __restrict__ xconv,
                                                       const float* __restrict__ xpw, float* __restrict__ xdbl){
  __shared__ unsigned short As[64][40];
  __shared__ unsigned short Ws[64][40];
  __shared__ float ct[64][65];
  int tid = threadIdx.x;
  int lane = tid & 63, w = tid >> 6;
  int wy = w >> 1, wx = w & 1;
  int frow = lane & 15, fk = (lane >> 4) * 8;
  int m0 = blockIdx.x * 64;
  int bk = blockIdx.z; int b = bk >> 2, dir = bk & 3;
  const float* Wk = xpw + (size_t)dir*44*384;
  int mA0 = tid >> 3, mA1 = (tid + 256) >> 3;
  int k4 = (tid & 7)*4;
  size_t rowA0 = (size_t)(b*1024 + mapdir_(dir, m0 + mA0))*384;
  size_t rowA1 = (size_t)(b*1024 + mapdir_(dir, m0 + mA1))*384;
  f32x4 acc[2][2];
  #pragma unroll
  for (int i=0;i<2;i++)
    #pragma unroll
    for (int j=0;j<2;j++) acc[i][j] = (f32x4){0.f,0.f,0.f,0.f};

  for (int k0 = 0; k0 < 384; k0 += 32){
    {
      float4 v0 = *(const float4*)&xconv[rowA0 + k0 + k4];
      As[mA0][k4+0]=f2bf_(v0.x); As[mA0][k4+1]=f2bf_(v0.y);
      As[mA0][k4+2]=f2bf_(v0.z); As[mA0][k4+3]=f2bf_(v0.w);
      float4 v1 = *(const float4*)&xconv[rowA1 + k0 + k4];
      As[mA1][k4+0]=f2bf_(v1.x); As[mA1][k4+1]=f2bf_(v1.y);
      As[mA1][k4+2]=f2bf_(v1.z); As[mA1][k4+3]=f2bf_(v1.w);
    }
    #pragma unroll
    for (int r=0;r<2;r++){
      int fid = tid + 256*r;
      int n = fid >> 3, kw = (fid & 7)*4;
      float4 v = (n < 44) ? *(const float4*)&Wk[(size_t)n*384 + k0 + kw] : make_float4(0.f,0.f,0.f,0.f);
      Ws[n][kw+0]=f2bf_(v.x); Ws[n][kw+1]=f2bf_(v.y);
      Ws[n][kw+2]=f2bf_(v.z); Ws[n][kw+3]=f2bf_(v.w);
    }
    __syncthreads();
    short8 af[2], bfr[2];
    #pragma unroll
    for (int mt=0;mt<2;mt++) af[mt] = *(const short8*)&As[wy*32 + mt*16 + frow][fk];
    #pragma unroll
    for (int nt=0;nt<2;nt++) bfr[nt] = *(const short8*)&Ws[wx*32 + nt*16 + frow][fk];
    #pragma unroll
    for (int mt=0;mt<2;mt++)
      #pragma unroll
      for (int nt=0;nt<2;nt++)
        acc[mt][nt] = __builtin_amdgcn_mfma_f32_16x16x32_bf16(af[mt], bfr[nt], acc[mt][nt], 0, 0, 0);
    __syncthreads();
  }
  #pragma unroll
  for (int mt=0;mt<2;mt++){
    int row0 = wy*32 + mt*16 + (lane>>4)*4;
    #pragma unroll
    for (int nt=0;nt<2;nt++){
      int cg = wx*32 + nt*16 + frow;
      #pragma unroll
      for (int i=0;i<4;i++) ct[row0+i][cg] = acc[mt][nt][i];
    }
  }
  __syncthreads();
  float* Cb = xdbl + (size_t)bk*44*1024;
  #pragma unroll
  for (int it=0; it<11; it++){
    int idx = tid + 256*it;            // 44*64 = 2816 = 11*256
    int c = idx >> 6, l = idx & 63;
    Cb[(size_t)c*1024 + m0 + l] = ct[l][c];
  }
}

// ---------------- selective scan pass A: chunk summaries, CL=16, 64 chunks.
// P[n] = exp(Ar[n]*sum(delta)) exactly (product of exps). h-loop uses guarded fast-exp chain.
__global__ __launch_bounds__(256, 4) void scan_chunks(const float* __restrict__ xconv, const float* __restrict__ xdbl,
    const float* __restrict__ dtw_all, const float* __restrict__ dtb_all, const float* __restrict__ alog_all,
    float* __restrict__ Pa, float* __restrict__ Sa){
  __shared__ float xs[28][64];
  int tid = threadIdx.x;
  int dl = tid & 63, cs = tid >> 6;
  int d = blockIdx.x*64 + dl;
  int chunk = blockIdx.y*4 + cs;
  int bk = blockIdx.z; int b = bk >> 2, k = bk & 3;
  const float* xd = xdbl + (size_t)bk*44*1024;
  int L0 = blockIdx.y*64;
  for (int t = tid; t < 28*16; t += 256){
    int c = t >> 4, col = (t & 15) << 2;
    float4 v = *(const float4*)&xd[(size_t)c*1024 + L0 + col];
    *(float4*)&xs[c][col] = v;
  }
  float dtw[12];
  #pragma unroll
  for (int r=0;r<12;r++) dtw[r] = dtw_all[(size_t)(k*384 + d)*12 + r];
  float dtb = dtb_all[k*384 + d];
  float Ar[16];
  #pragma unroll
  for (int n=0;n<16;n++) Ar[n] = -__expf(alog_all[(size_t)(k*384 + d)*16 + n]);
  bool linear = true;
  #pragma unroll
  for (int n=0;n<16;n++) linear = linear && (fabsf(Ar[n] + (float)(n+1)) <= 1e-3f*(float)(n+1));
  float h[16];
  #pragma unroll
  for (int n=0;n<16;n++) h[n]=0.f;
  float sdelta = 0.f;
  __syncthreads();
  int l0 = chunk*16, c0 = cs*16;
  if (linear){
    for (int li=0; li<16; li++){
      int l = l0 + li, col = c0 + li;
      float u = xconv[((size_t)(b*1024 + mapdir_(k, l)))*384 + d];
      float dr = dtb;
      #pragma unroll
      for (int r=0;r<12;r++) dr = fmaf(dtw[r], xs[r][col], dr);
      float delta = softplusf_(dr);
      float du = delta * u;
      sdelta += delta;
      float q = __expf(-delta), e = 1.f;
      #pragma unroll
      for (int n=0;n<16;n++){
        e *= q;
        h[n] = fmaf(e, h[n], du * xs[12+n][col]);
      }
    }
  } else {
    for (int li=0; li<16; li++){
      int l = l0 + li, col = c0 + li;
      float u = xconv[((size_t)(b*1024 + mapdir_(k, l)))*384 + d];
      float dr = dtb;
      #pragma unroll
      for (int r=0;r<12;r++) dr = fmaf(dtw[r], xs[r][col], dr);
      float delta = softplusf_(dr);
      float du = delta * u;
      sdelta += delta;
      #pragma unroll
      for (int n=0;n<16;n++){
        float e = __expf(delta * Ar[n]);
        h[n] = fmaf(e, h[n], du * xs[12+n][col]);
      }
    }
  }
  size_t base = (((size_t)bk*64 + chunk)*16)*384 + d;
  #pragma unroll
  for (int n=0;n<16;n++){
    Pa[base + (size_t)n*384] = __expf(sdelta * Ar[n]);
    Sa[base + (size_t)n*384] = h[n];
  }
}

// ---------------- pass B: serial chain over 64 chunk states; writes Hinit IN-PLACE into Pa.
__global__ __launch_bounds__(256) void scan_chain(float* __restrict__ Pa, const float* __restrict__ Sa){
  int dl = threadIdx.x & 63, nl = threadIdx.x >> 6;
  int d = blockIdx.x*64 + dl;
  int n = blockIdx.y*4 + nl;
  int bk = blockIdx.z;
  float h = 0.f;
  for (int c=0;c<64;c++){
    size_t idx = (((size_t)bk*64 + c)*16 + n)*384 + d;
    float p = Pa[idx], s = Sa[idx];
    Pa[idx] = h;
    h = fmaf(p, h, s);
  }
}

// ---------------- pass C: re-scan with Hinit (in Pa), emit y. LDS-stages all 44 xdbl rows.
__global__ __launch_bounds__(256, 4) void scan_emit(const float* __restrict__ xconv, const float* __restrict__ xdbl,
    const float* __restrict__ dtw_all, const float* __restrict__ dtb_all, const float* __restrict__ alog_all,
    const float* __restrict__ Ds, const float* __restrict__ Hinit, float* __restrict__ yout){
  __shared__ float xs[44][64];
  int tid = threadIdx.x;
  int dl = tid & 63, cs = tid >> 6;
  int d = blockIdx.x*64 + dl;
  int chunk = blockIdx.y*4 + cs;
  int bk = blockIdx.z; int b = bk >> 2, k = bk & 3;
  const float* xd = xdbl + (size_t)bk*44*1024;
  int L0 = blockIdx.y*64;
  for (int t = tid; t < 44*16; t += 256){
    int c = t >> 4, col = (t & 15) << 2;
    float4 v = *(const float4*)&xd[(size_t)c*1024 + L0 + col];
    *(float4*)&xs[c][col] = v;
  }
  float dtw[12];
  #pragma unroll
  for (int r=0;r<12;r++) dtw[r] = dtw_all[(size_t)(k*384 + d)*12 + r];
  float dtb = dtb_all[k*384 + d];
  float Dv = Ds[k*384 + d];
  float Ar[16];
  #pragma unroll
  for (int n=0;n<16;n++) Ar[n] = -__expf(alog_all[(size_t)(k*384 + d)*16 + n]);
  bool linear = true;
  #pragma unroll
  for (int n=0;n<16;n++) linear = linear && (fabsf(Ar[n] + (float)(n+1)) <= 1e-3f*(float)(n+1));
  float h[16];
  size_t hbase = (((size_t)bk*64 + chunk)*16)*384 + d;
  #pragma unroll
  for (int n=0;n<16;n++) h[n] = Hinit[hbase + (size_t)n*384];
  __syncthreads();
  int l0 = chunk*16, c0 = cs*16;
  if (linear){
    for (int li=0; li<16; li++){
      int l = l0 + li, col = c0 + li;
      float u = xconv[((size_t)(b*1024 + mapdir_(k, l)))*384 + d];
      float dr = dtb;
      #pragma unroll
      for (int r=0;r<12;r++) dr = fmaf(dtw[r], xs[r][col], dr);
      float delta = softplusf_(dr);
      float du = delta * u;
      float y = Dv * u;
      float q = __expf(-delta), e = 1.f;
      #pragma unroll
      for (int n=0;n<16;n++){
        e *= q;
        h[n] = fmaf(e, h[n], du * xs[12+n][col]);
        y = fmaf(h[n], xs[28+n][col], y);
      }
      yout[((size_t)bk*1024 + l)*384 + d] = y;
    }
  } else {
    for (int li=0; li<16; li++){
      int l = l0 + li, col = c0 + li;
      float u = xconv[((size_t)(b*1024 + mapdir_(k, l)))*384 + d];
      float dr = dtb;
      #pragma unroll
      for (int r=0;r<12;r++) dr = fmaf(dtw[r], xs[r][col], dr);
      float delta = softplusf_(dr);
      float du = delta * u;
      float y = Dv * u;
      #pragma unroll
      for (int n=0;n<16;n++){
        float e = __expf(delta * Ar[n]);
        h[n] = fmaf(e, h[n], du * xs[12+n][col]);
        y = fmaf(h[n], xs[28+n][col], y);
      }
      yout[((size_t)bk*1024 + l)*384 + d] = y;
    }
  }
}

// ---------------- merge 4 directions + LN(384) + *silu(z) -> gated pos-major
__global__ __launch_bounds__(64) void merge_ln(const float* __restrict__ ysc, const float* __restrict__ xz,
    const float* __restrict__ ong, const float* __restrict__ onb, float* __restrict__ gated){
  int bl = blockIdx.x; int b = bl >> 10, l = bl & 1023;
  int lane = threadIdx.x;
  int p1 = ((l & 31) << 5) | (l >> 5);
  const float* y0 = ysc + ((size_t)(b*4+0)*1024 + l)*384;
  const float* y1 = ysc + ((size_t)(b*4+1)*1024 + p1)*384;
  const float* y2 = ysc + ((size_t)(b*4+2)*1024 + (1023-l))*384;
  const float* y3 = ysc + ((size_t)(b*4+3)*1024 + (1023-p1))*384;
  float v[6]; float s = 0.f, s2 = 0.f;
  #pragma unroll
  for (int r=0;r<6;r++){
    int d = lane + 64*r;
    float t = y0[d] + y1[d] + y2[d] + y3[d];
    v[r] = t; s += t; s2 += t*t;
  }
  #pragma unroll
  for (int off=32; off; off>>=1){ s += __shfl_xor(s, off, 64); s2 += __shfl_xor(s2, off, 64); }
  float mean = s*(1.f/384.f);
  float var = s2*(1.f/384.f) - mean*mean;
  float rstd = rsqrtf(var + EPSF);
  const float* zrow = xz + (size_t)bl*768 + 384;
  float* grow = gated + (size_t)bl*384;
  #pragma unroll
  for (int r=0;r<6;r++){
    int d = lane + 64*r;
    float z = zrow[d];
    grow[d] = ((v[r]-mean)*rstd*ong[d] + onb[d]) * siluf_(z);
  }
}

// ---------------- high path depthwise 3x3 + BN (+ReLU)
template<int RELU>
__global__ __launch_bounds__(576) void dwconv_bn(const float* __restrict__ hin,
    const float* __restrict__ dw, const float* __restrict__ bn, float* __restrict__ hout){
  int bl = blockIdx.x; int b = bl >> 10, l = bl & 1023;
  int i = l >> 5, j = l & 31;
  int d = threadIdx.x;
  float w[9];
  #pragma unroll
  for (int t=0;t<9;t++) w[t] = dw[d*9+t];
  float acc = 0.f;
  #pragma unroll
  for (int di=-1;di<=1;di++){
    int ii = i+di; if (ii < 0 || ii > 31) continue;
    #pragma unroll
    for (int dj=-1;dj<=1;dj++){
      int jj = j+dj; if (jj < 0 || jj > 31) continue;
      acc += w[(di+1)*3 + (dj+1)] * hin[((size_t)(b*1024 + ii*32 + jj))*576 + d];
    }
  }
  float sc = bn[d] * rsqrtf(bn[3*576+d] + EPSF);
  float vv = (acc - bn[2*576+d])*sc + bn[576+d];
  if (RELU) vv = fmaxf(vv, 0.f);
  hout[(size_t)bl*576 + d] = vv;
}

// ---------------- spatial partial sums of h2: grid (9, 4, 32), each block sums 32 positions
__global__ __launch_bounds__(256) void mean576p(const float* __restrict__ h2, float* __restrict__ partials){
  __shared__ float red[256];
  int dg = blockIdx.x, b = blockIdx.y, ch = blockIdx.z;
  int dl = threadIdx.x & 63, lq = threadIdx.x >> 6;
  int d = dg*64 + dl;
  int l0 = ch*32;
  float ps = 0.f;
  #pragma unroll
  for (int li = 0; li < 8; li++){
    int l = l0 + lq + li*4;
    ps += h2[((size_t)(b*1024 + l))*576 + d];
  }
  red[threadIdx.x] = ps;
  __syncthreads();
  if (threadIdx.x < 64){
    float ssum = red[threadIdx.x] + red[threadIdx.x+64] + red[threadIdx.x+128] + red[threadIdx.x+192];
    partials[((size_t)(b*32 + ch))*576 + dg*64 + threadIdx.x] = ssum;
  }
}

// ---------------- SE gate (sums 32 partials per channel, then two tiny GEMVs)
__global__ __launch_bounds__(256) void se_gate(const float* __restrict__ partials,
    const float* __restrict__ rw, const float* __restrict__ rb,
    const float* __restrict__ ew, const float* __restrict__ eb, float* __restrict__ gate4){
  __shared__ float s_ld[576];
  __shared__ float r_ld[144];
  int b = blockIdx.x, t = threadIdx.x;
  for (int c=t; c<576; c+=256){
    float s = 0.f;
    #pragma unroll
    for (int ch=0; ch<32; ch++) s += partials[((size_t)(b*32 + ch))*576 + c];
    s_ld[c] = s * (1.f/1024.f);
  }
  __syncthreads();
  if (t < 144){
    float a = rb[t];
    for (int c=0;c<576;c++) a = fmaf(rw[(size_t)t*576+c], s_ld[c], a);
    r_ld[t] = fmaxf(a, 0.f);
  }
  __syncthreads();
  for (int d=t; d<576; d+=256){
    float a = eb[d];
    for (int j=0;j<144;j++) a = fmaf(ew[(size_t)d*144+j], r_ld[j], a);
    gate4[b*576+d] = sigmoidf_(a);
  }
}

// ---------------- wavelet reconstruct into A1 pos-major cols 0..192 (lda=320)
__global__ __launch_bounds__(192) void recon(const float* __restrict__ xllout, const float* __restrict__ h2o,
                                             float* __restrict__ A1){
  int bl = blockIdx.x; int b = bl >> 10, lr = bl & 1023;
  int c = threadIdx.x;
  int i = lr >> 5, j = lr & 31;
  float f0 = xllout[(size_t)bl*192 + c];
  const float* hp = &h2o[(size_t)bl*576 + 3*c];
  float f1 = hp[0], f2 = hp[1], f3 = hp[2];
  float v00 = 0.5f*(f0 - f1 - f2 + f3);
  float v01 = 0.5f*(f0 - f1 + f2 - f3);
  float v10 = 0.5f*(f0 + f1 - f2 - f3);
  float v11 = 0.5f*(f0 + f1 + f2 + f3);
  size_t base = ((size_t)b*4096 + (size_t)(2*i)*64 + 2*j)*320 + c;
  A1[base]            = v00;
  A1[base + 320]      = v01;
  A1[base + 64*320]   = v10;
  A1[base + 65*320]   = v11;
}

extern "C" void kernel_launch(void* const* d_in, const int* in_sizes, int n_in,
                              void* d_out, int out_size, void* d_ws, size_t ws_size,
                              hipStream_t stream) {
  const float* x         = (const float*)d_in[0];
  const float* in_proj_w = (const float*)d_in[1];
  const float* conv_w    = (const float*)d_in[2];
  const float* conv_b    = (const float*)d_in[3];
  const float* x_proj_w  = (const float*)d_in[4];
  const float* dt_proj_w = (const float*)d_in[5];
  const float* dt_proj_b = (const float*)d_in[6];
  const float* A_logs    = (const float*)d_in[7];
  const float* Dsp       = (const float*)d_in[8];
  const float* out_norm_g= (const float*)d_in[9];
  const float* out_norm_b= (const float*)d_in[10];
  const float* out_proj_w= (const float*)d_in[11];
  const float* norm_g    = (const float*)d_in[12];
  const float* norm_b    = (const float*)d_in[13];
  const float* lp_dw1_w  = (const float*)d_in[14];
  const float* lp_bn1    = (const float*)d_in[15];
  const float* lp_dw2_w  = (const float*)d_in[16];
  const float* lp_bn2    = (const float*)d_in[17];
  const float* se_rw     = (const float*)d_in[18];
  const float* se_rb     = (const float*)d_in[19];
  const float* se_ew     = (const float*)d_in[20];
  const float* se_eb     = (const float*)d_in[21];
  const float* lp_pw_w   = (const float*)d_in[22];
  const float* lp_bn3    = (const float*)d_in[23];
  const float* proj_w    = (const float*)d_in[24];
  const float* proj_bn   = (const float*)d_in[25];
  float* out = (float*)d_out;
  float* ws = (float*)d_ws;

  // time-phased workspace plan (floats) — total 21,959,168 floats = 87.8 MB
  float* xhigh = ws;                   // 2359296  : wav_dec -> dwconv_bn1
  float* xz    = xhigh + 2359296;      // 3145728  : in_proj -> merge_ln      (later h2)
  float* xconv = xz + 3145728;         // 1572864  : dwconv_silu -> scan C    (later gated)
  float* xdbl  = xconv + 1572864;      // 720896   : xproj -> scan C
  float* Pa    = xdbl + 720896;        // 6291456  : scanA -> chain(in-place Hinit) -> scanC  (later h1, h2o)
  float* Sa    = Pa + 6291456;         // 6291456  : scanA -> chain -> yscan -> merge_ln; then A1 (16384*320)
  float* xll   = Sa + 6291456;         // 786432   : wav_dec -> ln192         (later xllout)
  float* xln   = xll + 786432;         // 786432   : ln192 -> in_proj         (later partials 73728)
  float* smean = xln + 786432;         // 2304     (unused now)
  float* gate4 = smean + 2304;         // 2304
  float* Hinit = Pa;       // chain overwrites Pa in place with per-chunk init states
  float* yscan = Sa;       // pass C output (Sa dead after chain)
  float* gated = xconv;    // merge_ln output (xconv dead after pass C)
  float* xllout= xll;      // out_proj output (xll dead after ln192)
  float* h1    = Pa;       // dwconv_bn1 output (Pa dead after pass C)
  float* h2    = xz;       // dwconv_bn2 output (xz dead after merge_ln)
  float* h2o   = Pa;       // pw gemm output (h1 dead after dwconv_bn2)
  float* A1    = Sa;       // recon + xid_t output (yscan dead after merge_ln); 5,242,880 floats
  float* partials = xln;   // mean576p partials (xln dead after in_proj); 73728 floats

  wav_dec<<<dim3(128), dim3(256), 0, stream>>>(x, xll, xhigh);
  ln192<<<dim3(4096), dim3(64), 0, stream>>>(xll, norm_g, norm_b, xln);
  gemm_mfma<0><<<dim3(64,12), dim3(256), 0, stream>>>(xln, in_proj_w, xz, 4096, 768, 192, 192,
                                                      nullptr, nullptr, nullptr);
  dwconv_silu<<<dim3(4096), dim3(384), 0, stream>>>(xz, conv_w, conv_b, xconv);
  gemm_xproj_mfma<<<dim3(16,1,16), dim3(256), 0, stream>>>(xconv, x_proj_w, xdbl);
  scan_chunks<<<dim3(6,16,16), dim3(256), 0, stream>>>(xconv, xdbl, dt_proj_w, dt_proj_b, A_logs, Pa, Sa);
  scan_chain<<<dim3(6,4,16), dim3(256), 0, stream>>>(Pa, Sa);
  scan_emit<<<dim3(6,16,16), dim3(256), 0, stream>>>(xconv, xdbl, dt_proj_w, dt_proj_b, A_logs, Dsp, Hinit, yscan);
  merge_ln<<<dim3(4096), dim3(64), 0, stream>>>(yscan, xz, out_norm_g, out_norm_b, gated);
  gemm_mfma<0><<<dim3(64,3), dim3(256), 0, stream>>>(gated, out_proj_w, xllout, 4096, 192, 384, 384,
                                                     nullptr, nullptr, nullptr);
  xid_t<<<dim3(256), dim3(256), 0, stream>>>(x, A1);
  dwconv_bn<1><<<dim3(4096), dim3(576), 0, stream>>>(xhigh, lp_dw1_w, lp_bn1, h1);
  dwconv_bn<0><<<dim3(4096), dim3(576), 0, stream>>>(h1, lp_dw2_w, lp_bn2, h2);
  mean576p<<<dim3(9,4,32), dim3(256), 0, stream>>>(h2, partials);
  se_gate<<<dim3(4), dim3(256), 0, stream>>>(partials, se_rw, se_rb, se_ew, se_eb, gate4);
  gemm_mfma<2><<<dim3(64,9), dim3(256), 0, stream>>>(h2, lp_pw_w, h2o, 4096, 576, 576, 576,
                                                     gate4, lp_bn3, nullptr);
  recon<<<dim3(4096), dim3(192), 0, stream>>>(xllout, h2o, A1);
  gemm_mfma<3><<<dim3(256,5), dim3(256), 0, stream>>>(A1, proj_w, out, 16384, 320, 320, 320,
                                                      nullptr, proj_bn, x);
}